// Round 6
// baseline (638.213 us; speedup 1.0000x reference)
//
#include <hip/hip_runtime.h>
#include <hip/hip_bf16.h>
#include <stdint.h>

#define F_IN 512
#define HID 32
#define HEADS 8
#define C1 (HEADS*HID)   // 256
#define CLS 64
#define NEG 0.2f
#define EPS 1e-16f

typedef __bf16 bf16x8 __attribute__((ext_vector_type(8)));
typedef __bf16 bf16x4 __attribute__((ext_vector_type(4)));
typedef __bf16 bf16x2 __attribute__((ext_vector_type(2)));
typedef float  f32x4  __attribute__((ext_vector_type(4)));

__device__ __forceinline__ float leaky(float v) { return v > 0.f ? v : NEG * v; }

// ---------------- fp32 -> bf16 conversions ----------------
__global__ __launch_bounds__(256) void cvt_x(const float* __restrict__ x,
    __bf16* __restrict__ xb, int total8) {
  int i = blockIdx.x * 256 + threadIdx.x;
  if (i >= total8) return;
  const float4* p = (const float4*)(x + (size_t)i * 8);
  float4 a = p[0], b = p[1];
  bf16x8 o;
  o[0] = (__bf16)a.x; o[1] = (__bf16)a.y; o[2] = (__bf16)a.z; o[3] = (__bf16)a.w;
  o[4] = (__bf16)b.x; o[5] = (__bf16)b.y; o[6] = (__bf16)b.z; o[7] = (__bf16)b.w;
  *(bf16x8*)(xb + (size_t)i * 8) = o;
}

__global__ __launch_bounds__(256) void cvt_w1t(const float* __restrict__ W1,
    __bf16* __restrict__ w1t) {
  int i = blockIdx.x * 256 + threadIdx.x;
  int o0 = i * 8;
  int c = o0 >> 9, k0 = o0 & 511;
  bf16x8 o;
#pragma unroll
  for (int j = 0; j < 8; j++) o[j] = (__bf16)W1[(size_t)(k0 + j) * C1 + c];
  *(bf16x8*)(w1t + (size_t)o0) = o;
}

__global__ __launch_bounds__(256) void cvt_w2t(const float* __restrict__ W2,
    __bf16* __restrict__ w2t) {
  int i = blockIdx.x * 256 + threadIdx.x;
  if (i >= CLS * C1 / 8) return;
  int o0 = i * 8;
  int c = o0 >> 8, k0 = o0 & 255;
  bf16x8 o;
#pragma unroll
  for (int j = 0; j < 8; j++) o[j] = (__bf16)W2[(size_t)(k0 + j) * CLS + c];
  *(bf16x8*)(w2t + (size_t)o0) = o;
}

// ---------------- MFMA GEMM1: h1[M,256] = xb[M,512] @ w1t^T, out bf16 ----------------
__global__ __launch_bounds__(256) void gemm1_mfma(const __bf16* __restrict__ A,
    const __bf16* __restrict__ Bt, __bf16* __restrict__ C, int M) {
  __shared__ __bf16 Al[128 * 32];
  __shared__ __bf16 Bl[128 * 32];
  const int tid  = threadIdx.x;
  const int lane = tid & 63;
  const int wave = tid >> 6;
  const int lm = lane & 15, q = lane >> 4;
  const int wr = (wave >> 1) * 64, wc = (wave & 1) * 64;
  const int bm = blockIdx.y * 128, bn = blockIdx.x * 128;

  const int srow = tid >> 2;
  const int skc  = (tid & 3) * 8;

  f32x4 acc[4][4];
#pragma unroll
  for (int i = 0; i < 4; i++)
#pragma unroll
    for (int j = 0; j < 4; j++) acc[i][j] = (f32x4){0.f, 0.f, 0.f, 0.f};

  const int ra0 = min(bm + srow, M - 1);
  const int ra1 = min(bm + srow + 64, M - 1);
  const int rb0 = bn + srow, rb1 = bn + srow + 64;

  bf16x8 va0, va1, vb0, vb1;
  va0 = *(const bf16x8*)(A + (size_t)ra0 * 512 + skc);
  va1 = *(const bf16x8*)(A + (size_t)ra1 * 512 + skc);
  vb0 = *(const bf16x8*)(Bt + (size_t)rb0 * 512 + skc);
  vb1 = *(const bf16x8*)(Bt + (size_t)rb1 * 512 + skc);

  for (int kk = 0; kk < 16; kk++) {
    __syncthreads();
    *(bf16x8*)(Al + srow * 32 + skc)        = va0;
    *(bf16x8*)(Al + (srow + 64) * 32 + skc) = va1;
    *(bf16x8*)(Bl + srow * 32 + skc)        = vb0;
    *(bf16x8*)(Bl + (srow + 64) * 32 + skc) = vb1;
    __syncthreads();
    if (kk + 1 < 16) {
      const int k0 = (kk + 1) * 32;
      va0 = *(const bf16x8*)(A + (size_t)ra0 * 512 + k0 + skc);
      va1 = *(const bf16x8*)(A + (size_t)ra1 * 512 + k0 + skc);
      vb0 = *(const bf16x8*)(Bt + (size_t)rb0 * 512 + k0 + skc);
      vb1 = *(const bf16x8*)(Bt + (size_t)rb1 * 512 + k0 + skc);
    }
    bf16x8 af[4], bfr[4];
#pragma unroll
    for (int mi = 0; mi < 4; mi++)
      af[mi] = *(const bf16x8*)(Al + (wr + mi * 16 + lm) * 32 + q * 8);
#pragma unroll
    for (int ni = 0; ni < 4; ni++)
      bfr[ni] = *(const bf16x8*)(Bl + (wc + ni * 16 + lm) * 32 + q * 8);
#pragma unroll
    for (int mi = 0; mi < 4; mi++)
#pragma unroll
      for (int ni = 0; ni < 4; ni++)
        acc[mi][ni] = __builtin_amdgcn_mfma_f32_16x16x32_bf16(af[mi], bfr[ni], acc[mi][ni], 0, 0, 0);
  }

#pragma unroll
  for (int mi = 0; mi < 4; mi++) {
#pragma unroll
    for (int ni = 0; ni < 4; ni++) {
      const int col = bn + wc + ni * 16 + lm;
#pragma unroll
      for (int r = 0; r < 4; r++) {
        const int row = bm + wr + mi * 16 + q * 4 + r;
        if (row < M) C[(size_t)row * C1 + col] = (__bf16)acc[mi][ni][r];
      }
    }
  }
}

// ---------------- MFMA GEMM2: h2b[M,64](bf16) = o1[M,256] @ w2t^T ----------------
__global__ __launch_bounds__(256) void gemm2_mfma(const __bf16* __restrict__ A,
    const __bf16* __restrict__ Bt, __bf16* __restrict__ C, int M) {
  __shared__ __bf16 Al[128 * 32];
  __shared__ __bf16 Bl[64 * 32];
  const int tid  = threadIdx.x;
  const int lane = tid & 63;
  const int wave = tid >> 6;
  const int lm = lane & 15, q = lane >> 4;
  const int wr = (wave >> 1) * 64, wc = (wave & 1) * 32;
  const int bm = blockIdx.x * 128;

  const int srow = tid >> 2;
  const int skc  = (tid & 3) * 8;

  f32x4 acc[4][2];
#pragma unroll
  for (int i = 0; i < 4; i++)
#pragma unroll
    for (int j = 0; j < 2; j++) acc[i][j] = (f32x4){0.f, 0.f, 0.f, 0.f};

  const int ra0 = min(bm + srow, M - 1);
  const int ra1 = min(bm + srow + 64, M - 1);

  bf16x8 va0, va1, vb;
  va0 = *(const bf16x8*)(A + (size_t)ra0 * C1 + skc);
  va1 = *(const bf16x8*)(A + (size_t)ra1 * C1 + skc);
  vb  = *(const bf16x8*)(Bt + (size_t)srow * C1 + skc);

  for (int kk = 0; kk < 8; kk++) {
    __syncthreads();
    *(bf16x8*)(Al + srow * 32 + skc)        = va0;
    *(bf16x8*)(Al + (srow + 64) * 32 + skc) = va1;
    *(bf16x8*)(Bl + srow * 32 + skc)        = vb;
    __syncthreads();
    if (kk + 1 < 8) {
      const int k0 = (kk + 1) * 32;
      va0 = *(const bf16x8*)(A + (size_t)ra0 * C1 + k0 + skc);
      va1 = *(const bf16x8*)(A + (size_t)ra1 * C1 + k0 + skc);
      vb  = *(const bf16x8*)(Bt + (size_t)srow * C1 + k0 + skc);
    }
    bf16x8 af[4], bfr[2];
#pragma unroll
    for (int mi = 0; mi < 4; mi++)
      af[mi] = *(const bf16x8*)(Al + (wr + mi * 16 + lm) * 32 + q * 8);
#pragma unroll
    for (int ni = 0; ni < 2; ni++)
      bfr[ni] = *(const bf16x8*)(Bl + (wc + ni * 16 + lm) * 32 + q * 8);
#pragma unroll
    for (int mi = 0; mi < 4; mi++)
#pragma unroll
      for (int ni = 0; ni < 2; ni++)
        acc[mi][ni] = __builtin_amdgcn_mfma_f32_16x16x32_bf16(af[mi], bfr[ni], acc[mi][ni], 0, 0, 0);
  }

#pragma unroll
  for (int mi = 0; mi < 4; mi++) {
#pragma unroll
    for (int ni = 0; ni < 2; ni++) {
      const int col = wc + ni * 16 + lm;
#pragma unroll
      for (int r = 0; r < 4; r++) {
        const int row = bm + wr + mi * 16 + q * 4 + r;
        if (row < M) C[(size_t)row * CLS + col] = (__bf16)acc[mi][ni][r];
      }
    }
  }
}

// ---------------- attention score dots ----------------
// wave per node (4/block): lane covers 4 channels; head = lane>>3 (8 lanes/head)
__global__ __launch_bounds__(256) void att_scores1(const __bf16* __restrict__ h1,
    const float* __restrict__ asw, const float* __restrict__ adw,
    float* __restrict__ a_src, float* __restrict__ a_dst, int N) {
  const int t = threadIdx.x, lane = t & 63;
  const int n = blockIdx.x * 4 + (t >> 6);
  if (n >= N) return;
  bf16x4 x = *(const bf16x4*)(h1 + (size_t)n * C1 + lane * 4);
  const float4 wsv = *(const float4*)(asw + lane * 4);
  const float4 wdv = *(const float4*)(adw + lane * 4);
  float ps = (float)x[0] * wsv.x + (float)x[1] * wsv.y + (float)x[2] * wsv.z + (float)x[3] * wsv.w;
  float pd = (float)x[0] * wdv.x + (float)x[1] * wdv.y + (float)x[2] * wdv.z + (float)x[3] * wdv.w;
#pragma unroll
  for (int o = 1; o <= 4; o <<= 1) { ps += __shfl_xor(ps, o); pd += __shfl_xor(pd, o); }
  if ((lane & 7) == 0) {
    a_src[(size_t)n * 8 + (lane >> 3)] = ps;
    a_dst[(size_t)n * 8 + (lane >> 3)] = pd;
  }
}

// wave per node (4/block), reads bf16 h2
__global__ __launch_bounds__(256) void att_scores2(const __bf16* __restrict__ h2b,
    const float* __restrict__ asw, const float* __restrict__ adw,
    float* __restrict__ a_src, float* __restrict__ a_dst, int N) {
  const int t = threadIdx.x, lane = t & 63;
  const int n = blockIdx.x * 4 + (t >> 6);
  if (n >= N) return;
  float v  = (float)h2b[(size_t)n * CLS + lane];
  float ps = v * asw[lane];
  float pd = v * adw[lane];
#pragma unroll
  for (int o = 1; o < 64; o <<= 1) { ps += __shfl_xor(ps, o); pd += __shfl_xor(pd, o); }
  if (lane == 0) { a_src[n] = ps; a_dst[n] = pd; }
}

// ---------------- CSR build (dst-indexed; self-loops implicit) ----------------
__global__ __launch_bounds__(256) void count_deg(const int* __restrict__ ei,
    int* __restrict__ deg, int E) {
  int e = blockIdx.x * 256 + threadIdx.x;
  if (e < E) atomicAdd(&deg[ei[E + e]], 1);
}

__global__ __launch_bounds__(1024) void scan_rows(const int* __restrict__ deg,
    int* __restrict__ rowstart, int N) {
  __shared__ int wpart[16];
  __shared__ int s_carry;
  const int t = threadIdx.x, lane = t & 63, wid = t >> 6;
  if (t == 0) s_carry = 0;
  __syncthreads();
  for (int base = 0; base < N; base += 8192) {
    int i0 = base + t * 8;
    int d0[8], s8 = 0;
#pragma unroll
    for (int k = 0; k < 8; k++) { int i = i0 + k; d0[k] = (i < N) ? deg[i] : 0; s8 += d0[k]; }
    int v = s8;
#pragma unroll
    for (int off = 1; off < 64; off <<= 1) { int x = __shfl_up(v, off); if (lane >= off) v += x; }
    if (lane == 63) wpart[wid] = v;
    __syncthreads();
    if (wid == 0) {
      int w = (lane < 16) ? wpart[lane] : 0;
#pragma unroll
      for (int off = 1; off < 16; off <<= 1) { int x = __shfl_up(w, off); if (lane >= off) w += x; }
      if (lane < 16) wpart[lane] = w;
    }
    __syncthreads();
    int excl = s_carry + (wid > 0 ? wpart[wid - 1] : 0) + v - s8;
#pragma unroll
    for (int k = 0; k < 8; k++) { int i = i0 + k; if (i < N) rowstart[i] = excl; excl += d0[k]; }
    __syncthreads();
    if (t == 0) s_carry += wpart[15];
    __syncthreads();
  }
  if (t == 0) rowstart[N] = s_carry;
}

__global__ __launch_bounds__(256) void scatter_csr(const int* __restrict__ ei,
    int* __restrict__ cur, int* __restrict__ csr_src, int E) {
  int e = blockIdx.x * 256 + threadIdx.x;
  if (e >= E) return;
  int s = ei[e], d = ei[E + e];
  int pos = atomicAdd(&cur[d], 1);
  csr_src[pos] = s;
}

// ---------------- layer-1 gather: HEAD-SLICED, wave = (node, head) ----------------
// blockIdx&7 = head (XCD swizzle: per-XCD L2 holds one 3.2MB head slice of h1)
__global__ __launch_bounds__(256) void gather1(const int* __restrict__ rowstart,
    const int* __restrict__ csr_src, const __bf16* __restrict__ h1,
    const float* __restrict__ as1, const float* __restrict__ ad1,
    const float* __restrict__ b1, __bf16* __restrict__ o1, int N) {
  const int t = threadIdx.x, lane = t & 63;
  const int h = blockIdx.x & 7;
  const int d = (blockIdx.x >> 3) * 4 + (t >> 6);
  if (d >= N) return;
  const int r0 = rowstart[d], deg = rowstart[d + 1] - r0;
  const float addh = ad1[(size_t)d * 8 + h];
  const float self_sc = leaky(as1[(size_t)d * 8 + h] + addh);

  // scores: lane = edge index (first 64 edges cached in registers)
  int se = 0; float sc = -3.4e38f;
  if (lane < deg) { se = csr_src[r0 + lane]; sc = leaky(as1[(size_t)se * 8 + h] + addh); }
  float mx = sc;
  for (int j0 = 64; j0 < deg; j0 += 64) {   // rare tail
    int j = j0 + lane;
    if (j < deg) { int s2 = csr_src[r0 + j]; mx = fmaxf(mx, leaky(as1[(size_t)s2 * 8 + h] + addh)); }
  }
#pragma unroll
  for (int o = 1; o < 64; o <<= 1) mx = fmaxf(mx, __shfl_xor(mx, o));
  mx = fmaxf(mx, self_sc);

  float ex = (lane < deg) ? __expf(sc - mx) : 0.f;
  float sum = ex;
  for (int j0 = 64; j0 < deg; j0 += 64) {
    int j = j0 + lane;
    if (j < deg) { int s2 = csr_src[r0 + j]; sum += __expf(leaky(as1[(size_t)s2 * 8 + h] + addh) - mx); }
  }
#pragma unroll
  for (int o = 1; o < 64; o <<= 1) sum += __shfl_xor(sum, o);
  const float e_self = __expf(self_sc - mx);
  sum += e_self;
  const float inv = 1.f / (sum + EPS);
  const float alpha = ex * inv;            // 0 for padding lanes
  const float al_self = e_self * inv;

  // aggregation: (edge group e4, channel pair c16); 4 edges x 64B slices per iter
  const int e4 = lane >> 4, c16 = lane & 15;
  const size_t coff = (size_t)h * 32 + c16 * 2;
  float a0 = 0.f, a1 = 0.f;
  const int iters = (min(deg, 64) + 3) >> 2;
  for (int it = 0; it < iters; it++) {
    int j = it * 4 + e4;
    int   sj = __shfl(se, j);
    float aj = __shfl(alpha, j);           // 0 beyond deg -> harmless node-0 load
    bf16x2 x = *(const bf16x2*)(h1 + (size_t)sj * C1 + coff);
    a0 += aj * (float)x[0]; a1 += aj * (float)x[1];
  }
  for (int j0 = 64; j0 < deg; j0 += 64) {  // rare tail
    int j = j0 + lane;
    int se2 = 0; float al2 = 0.f;
    if (j < deg) { se2 = csr_src[r0 + j]; al2 = __expf(leaky(as1[(size_t)se2 * 8 + h] + addh) - mx) * inv; }
    const int it2 = (min(deg - j0, 64) + 3) >> 2;
    for (int it = 0; it < it2; it++) {
      int jj = it * 4 + e4;
      int   sj = __shfl(se2, jj);
      float aj = __shfl(al2, jj);
      bf16x2 x = *(const bf16x2*)(h1 + (size_t)sj * C1 + coff);
      a0 += aj * (float)x[0]; a1 += aj * (float)x[1];
    }
  }
  a0 += __shfl_xor(a0, 16); a1 += __shfl_xor(a1, 16);
  a0 += __shfl_xor(a0, 32); a1 += __shfl_xor(a1, 32);
  if (lane < 16) {
    bf16x2 xs = *(const bf16x2*)(h1 + (size_t)d * C1 + coff);
    a0 += al_self * (float)xs[0]; a1 += al_self * (float)xs[1];
    const float2 bb = *(const float2*)(b1 + coff);
    bf16x2 o;
    o[0] = (__bf16)fmaxf(a0 + bb.x, 0.f);
    o[1] = (__bf16)fmaxf(a1 + bb.y, 0.f);
    *(bf16x2*)(o1 + (size_t)d * C1 + coff) = o;
  }
}

// ---------------- layer-2 gather: 2-way CHANNEL-SLICED, wave = (node, slice) ----------------
// blockIdx&7: bit2 = slice (XCDs 0-3 slice0, 4-7 slice1); bits0-1 = node subchunk
// writes raw logits (fp32) to out; bias+log_softmax in final_lsm
__global__ __launch_bounds__(256) void gather2(const int* __restrict__ rowstart,
    const int* __restrict__ csr_src, const __bf16* __restrict__ h2b,
    const float* __restrict__ as2, const float* __restrict__ ad2,
    float* __restrict__ out, int N) {
  const int t = threadIdx.x, lane = t & 63;
  const int b = blockIdx.x & 7;
  const int sl = b >> 2;
  const int d = (blockIdx.x >> 3) * 16 + (b & 3) * 4 + (t >> 6);
  if (d >= N) return;
  const int r0 = rowstart[d], deg = rowstart[d + 1] - r0;
  const float addd = ad2[d];
  const float self_sc = leaky(as2[d] + addd);

  int se = 0; float sc = -3.4e38f;
  if (lane < deg) { se = csr_src[r0 + lane]; sc = leaky(as2[se] + addd); }
  float mx = sc;
  for (int j0 = 64; j0 < deg; j0 += 64) {
    int j = j0 + lane;
    if (j < deg) mx = fmaxf(mx, leaky(as2[csr_src[r0 + j]] + addd));
  }
#pragma unroll
  for (int o = 1; o < 64; o <<= 1) mx = fmaxf(mx, __shfl_xor(mx, o));
  mx = fmaxf(mx, self_sc);

  float ex = (lane < deg) ? __expf(sc - mx) : 0.f;
  float sum = ex;
  for (int j0 = 64; j0 < deg; j0 += 64) {
    int j = j0 + lane;
    if (j < deg) sum += __expf(leaky(as2[csr_src[r0 + j]] + addd) - mx);
  }
#pragma unroll
  for (int o = 1; o < 64; o <<= 1) sum += __shfl_xor(sum, o);
  const float e_self = __expf(self_sc - mx);
  sum += e_self;
  const float inv = 1.f / (sum + EPS);
  const float alpha = ex * inv;
  const float al_self = e_self * inv;

  const int e4 = lane >> 4, c16 = lane & 15;
  const size_t coff = (size_t)sl * 32 + c16 * 2;
  float a0 = 0.f, a1 = 0.f;
  const int iters = (min(deg, 64) + 3) >> 2;
  for (int it = 0; it < iters; it++) {
    int j = it * 4 + e4;
    int   sj = __shfl(se, j);
    float aj = __shfl(alpha, j);
    bf16x2 x = *(const bf16x2*)(h2b + (size_t)sj * CLS + coff);
    a0 += aj * (float)x[0]; a1 += aj * (float)x[1];
  }
  for (int j0 = 64; j0 < deg; j0 += 64) {
    int j = j0 + lane;
    int se2 = 0; float al2 = 0.f;
    if (j < deg) { se2 = csr_src[r0 + j]; al2 = __expf(leaky(as2[se2] + addd) - mx) * inv; }
    const int it2 = (min(deg - j0, 64) + 3) >> 2;
    for (int it = 0; it < it2; it++) {
      int jj = it * 4 + e4;
      int   sj = __shfl(se2, jj);
      float aj = __shfl(al2, jj);
      bf16x2 x = *(const bf16x2*)(h2b + (size_t)sj * CLS + coff);
      a0 += aj * (float)x[0]; a1 += aj * (float)x[1];
    }
  }
  a0 += __shfl_xor(a0, 16); a1 += __shfl_xor(a1, 16);
  a0 += __shfl_xor(a0, 32); a1 += __shfl_xor(a1, 32);
  if (lane < 16) {
    bf16x2 xs = *(const bf16x2*)(h2b + (size_t)d * CLS + coff);
    a0 += al_self * (float)xs[0]; a1 += al_self * (float)xs[1];
    float2 o; o.x = a0; o.y = a1;
    *(float2*)(out + (size_t)d * CLS + coff) = o;
  }
}

// ---------------- final: out = log_softmax(out + b2) in place; 4 nodes/block ----------------
__global__ __launch_bounds__(256) void final_lsm(float* __restrict__ out,
    const float* __restrict__ b2, int N) {
  const int t = threadIdx.x, c = t & 63;
  const int n = blockIdx.x * 4 + (t >> 6);
  if (n >= N) return;
  float v = out[(size_t)n * CLS + c] + b2[c];
  float mx = v;
#pragma unroll
  for (int o = 1; o < 64; o <<= 1) mx = fmaxf(mx, __shfl_xor(mx, o));
  float ex = __expf(v - mx);
  float sm = ex;
#pragma unroll
  for (int o = 1; o < 64; o <<= 1) sm += __shfl_xor(sm, o);
  out[(size_t)n * CLS + c] = v - mx - __logf(sm);
}

extern "C" void kernel_launch(void* const* d_in, const int* in_sizes, int n_in,
                              void* d_out, int out_size, void* d_ws, size_t ws_size,
                              hipStream_t stream) {
  const float* x        = (const float*)d_in[0];
  const int*   ei       = (const int*)d_in[1];
  const float* W1       = (const float*)d_in[2];
  const float* att_src1 = (const float*)d_in[3];
  const float* att_dst1 = (const float*)d_in[4];
  const float* b1       = (const float*)d_in[5];
  const float* W2       = (const float*)d_in[6];
  const float* att_src2 = (const float*)d_in[7];
  const float* att_dst2 = (const float*)d_in[8];
  const float* b2       = (const float*)d_in[9];
  float* out = (float*)d_out;

  const int N  = in_sizes[0] / F_IN;   // 50000
  const int E  = in_sizes[1] / 2;      // 800000

  char* ws = (char*)d_ws;
  size_t off = 0;
  auto alloc = [&](size_t bytes) -> void* {
    void* p = ws + off;
    off += (bytes + 255) & ~(size_t)255;
    return p;
  };
  __bf16* h1  = (__bf16*)alloc((size_t)N * C1 * 2);
  __bf16* o1  = (__bf16*)alloc((size_t)N * C1 * 2);
  float*  as1 = (float*)alloc((size_t)N * HEADS * 4);
  float*  ad1 = (float*)alloc((size_t)N * HEADS * 4);
  __bf16* h2b = (__bf16*)alloc((size_t)N * CLS * 2);
  float*  as2 = (float*)alloc((size_t)N * 4);
  float*  ad2 = (float*)alloc((size_t)N * 4);
  int* deg      = (int*)alloc((size_t)N * 4);
  int* rowstart = (int*)alloc((size_t)(N + 1) * 4);
  int* cur      = (int*)alloc((size_t)N * 4);
  int* csr_src  = (int*)alloc((size_t)E * 4);
  __bf16* xb  = (__bf16*)alloc((size_t)N * F_IN * 2);
  __bf16* w1t = (__bf16*)alloc((size_t)C1 * F_IN * 2);
  __bf16* w2t = (__bf16*)alloc((size_t)CLS * C1 * 2);

  // ---- bf16 conversions ----
  cvt_x<<<(N * F_IN / 8 + 255) / 256, 256, 0, stream>>>(x, xb, N * F_IN / 8);
  cvt_w1t<<<(C1 * F_IN / 8 + 255) / 256, 256, 0, stream>>>(W1, w1t);
  cvt_w2t<<<(CLS * C1 / 8 + 255) / 256, 256, 0, stream>>>(W2, w2t);

  // ---- CSR build (self-loops implicit in gather kernels) ----
  hipMemsetAsync(deg, 0, (size_t)N * 4, stream);
  count_deg<<<(E + 255) / 256, 256, 0, stream>>>(ei, deg, E);
  scan_rows<<<1, 1024, 0, stream>>>(deg, rowstart, N);
  hipMemcpyAsync(cur, rowstart, (size_t)N * 4, hipMemcpyDeviceToDevice, stream);
  scatter_csr<<<(E + 255) / 256, 256, 0, stream>>>(ei, cur, csr_src, E);

  // ---- layer 1 ----
  {
    dim3 g(C1 / 128, (N + 127) / 128);
    gemm1_mfma<<<g, 256, 0, stream>>>(xb, w1t, h1, N);
  }
  att_scores1<<<(N + 3) / 4, 256, 0, stream>>>(h1, att_src1, att_dst1, as1, ad1, N);
  gather1<<<((N + 3) / 4) * 8, 256, 0, stream>>>(rowstart, csr_src, h1, as1, ad1, b1, o1, N);

  // ---- layer 2 ----
  gemm2_mfma<<<(N + 127) / 128, 256, 0, stream>>>(o1, w2t, h2b, N);
  att_scores2<<<(N + 3) / 4, 256, 0, stream>>>(h2b, att_src2, att_dst2, as2, ad2, N);
  gather2<<<((N + 15) / 16) * 8, 256, 0, stream>>>(rowstart, csr_src, h2b, as2, ad2, out, N);

  // ---- bias + log_softmax ----
  final_lsm<<<(N + 3) / 4, 256, 0, stream>>>(out, b2, N);
}

// Round 7
// 481.456 us; speedup vs baseline: 1.3256x; 1.3256x over previous
//
#include <hip/hip_runtime.h>
#include <hip/hip_bf16.h>
#include <stdint.h>

#define F_IN 512
#define HID 32
#define HEADS 8
#define C1 (HEADS*HID)   // 256
#define CLS 64
#define NEG 0.2f
#define EPS 1e-16f

typedef __bf16 bf16x8 __attribute__((ext_vector_type(8)));
typedef __bf16 bf16x4 __attribute__((ext_vector_type(4)));
typedef float  f32x4  __attribute__((ext_vector_type(4)));

__device__ __forceinline__ float leaky(float v) { return v > 0.f ? v : NEG * v; }

// ---------------- fp32 -> bf16 conversions ----------------
__global__ __launch_bounds__(256) void cvt_x(const float* __restrict__ x,
    __bf16* __restrict__ xb, int total8) {
  int i = blockIdx.x * 256 + threadIdx.x;
  if (i >= total8) return;
  const float4* p = (const float4*)(x + (size_t)i * 8);
  float4 a = p[0], b = p[1];
  bf16x8 o;
  o[0] = (__bf16)a.x; o[1] = (__bf16)a.y; o[2] = (__bf16)a.z; o[3] = (__bf16)a.w;
  o[4] = (__bf16)b.x; o[5] = (__bf16)b.y; o[6] = (__bf16)b.z; o[7] = (__bf16)b.w;
  *(bf16x8*)(xb + (size_t)i * 8) = o;
}

__global__ __launch_bounds__(256) void cvt_w1t(const float* __restrict__ W1,
    __bf16* __restrict__ w1t) {
  int i = blockIdx.x * 256 + threadIdx.x;
  int o0 = i * 8;
  int c = o0 >> 9, k0 = o0 & 511;
  bf16x8 o;
#pragma unroll
  for (int j = 0; j < 8; j++) o[j] = (__bf16)W1[(size_t)(k0 + j) * C1 + c];
  *(bf16x8*)(w1t + (size_t)o0) = o;
}

__global__ __launch_bounds__(256) void cvt_w2t(const float* __restrict__ W2,
    __bf16* __restrict__ w2t) {
  int i = blockIdx.x * 256 + threadIdx.x;
  if (i >= CLS * C1 / 8) return;
  int o0 = i * 8;
  int c = o0 >> 8, k0 = o0 & 255;
  bf16x8 o;
#pragma unroll
  for (int j = 0; j < 8; j++) o[j] = (__bf16)W2[(size_t)(k0 + j) * CLS + c];
  *(bf16x8*)(w2t + (size_t)o0) = o;
}

// ---------------- MFMA GEMM1: h1[M,256] = xb[M,512] @ w1t^T, out bf16 ----------------
__global__ __launch_bounds__(256) void gemm1_mfma(const __bf16* __restrict__ A,
    const __bf16* __restrict__ Bt, __bf16* __restrict__ C, int M) {
  __shared__ __bf16 Al[128 * 32];
  __shared__ __bf16 Bl[128 * 32];
  const int tid  = threadIdx.x;
  const int lane = tid & 63;
  const int wave = tid >> 6;
  const int lm = lane & 15, q = lane >> 4;
  const int wr = (wave >> 1) * 64, wc = (wave & 1) * 64;
  const int bm = blockIdx.y * 128, bn = blockIdx.x * 128;

  const int srow = tid >> 2;
  const int skc  = (tid & 3) * 8;

  f32x4 acc[4][4];
#pragma unroll
  for (int i = 0; i < 4; i++)
#pragma unroll
    for (int j = 0; j < 4; j++) acc[i][j] = (f32x4){0.f, 0.f, 0.f, 0.f};

  const int ra0 = min(bm + srow, M - 1);
  const int ra1 = min(bm + srow + 64, M - 1);
  const int rb0 = bn + srow, rb1 = bn + srow + 64;

  bf16x8 va0, va1, vb0, vb1;
  va0 = *(const bf16x8*)(A + (size_t)ra0 * 512 + skc);
  va1 = *(const bf16x8*)(A + (size_t)ra1 * 512 + skc);
  vb0 = *(const bf16x8*)(Bt + (size_t)rb0 * 512 + skc);
  vb1 = *(const bf16x8*)(Bt + (size_t)rb1 * 512 + skc);

  for (int kk = 0; kk < 16; kk++) {
    __syncthreads();
    *(bf16x8*)(Al + srow * 32 + skc)        = va0;
    *(bf16x8*)(Al + (srow + 64) * 32 + skc) = va1;
    *(bf16x8*)(Bl + srow * 32 + skc)        = vb0;
    *(bf16x8*)(Bl + (srow + 64) * 32 + skc) = vb1;
    __syncthreads();
    if (kk + 1 < 16) {
      const int k0 = (kk + 1) * 32;
      va0 = *(const bf16x8*)(A + (size_t)ra0 * 512 + k0 + skc);
      va1 = *(const bf16x8*)(A + (size_t)ra1 * 512 + k0 + skc);
      vb0 = *(const bf16x8*)(Bt + (size_t)rb0 * 512 + k0 + skc);
      vb1 = *(const bf16x8*)(Bt + (size_t)rb1 * 512 + k0 + skc);
    }
    bf16x8 af[4], bfr[4];
#pragma unroll
    for (int mi = 0; mi < 4; mi++)
      af[mi] = *(const bf16x8*)(Al + (wr + mi * 16 + lm) * 32 + q * 8);
#pragma unroll
    for (int ni = 0; ni < 4; ni++)
      bfr[ni] = *(const bf16x8*)(Bl + (wc + ni * 16 + lm) * 32 + q * 8);
#pragma unroll
    for (int mi = 0; mi < 4; mi++)
#pragma unroll
      for (int ni = 0; ni < 4; ni++)
        acc[mi][ni] = __builtin_amdgcn_mfma_f32_16x16x32_bf16(af[mi], bfr[ni], acc[mi][ni], 0, 0, 0);
  }

#pragma unroll
  for (int mi = 0; mi < 4; mi++) {
#pragma unroll
    for (int ni = 0; ni < 4; ni++) {
      const int col = bn + wc + ni * 16 + lm;
#pragma unroll
      for (int r = 0; r < 4; r++) {
        const int row = bm + wr + mi * 16 + q * 4 + r;
        if (row < M) C[(size_t)row * C1 + col] = (__bf16)acc[mi][ni][r];
      }
    }
  }
}

// ---------------- MFMA GEMM2: h2b[M,64](bf16) = o1[M,256] @ w2t^T ----------------
__global__ __launch_bounds__(256) void gemm2_mfma(const __bf16* __restrict__ A,
    const __bf16* __restrict__ Bt, __bf16* __restrict__ C, int M) {
  __shared__ __bf16 Al[128 * 32];
  __shared__ __bf16 Bl[64 * 32];
  const int tid  = threadIdx.x;
  const int lane = tid & 63;
  const int wave = tid >> 6;
  const int lm = lane & 15, q = lane >> 4;
  const int wr = (wave >> 1) * 64, wc = (wave & 1) * 32;
  const int bm = blockIdx.x * 128;

  const int srow = tid >> 2;
  const int skc  = (tid & 3) * 8;

  f32x4 acc[4][2];
#pragma unroll
  for (int i = 0; i < 4; i++)
#pragma unroll
    for (int j = 0; j < 2; j++) acc[i][j] = (f32x4){0.f, 0.f, 0.f, 0.f};

  const int ra0 = min(bm + srow, M - 1);
  const int ra1 = min(bm + srow + 64, M - 1);

  bf16x8 va0, va1, vb;
  va0 = *(const bf16x8*)(A + (size_t)ra0 * C1 + skc);
  va1 = *(const bf16x8*)(A + (size_t)ra1 * C1 + skc);
  vb  = *(const bf16x8*)(Bt + (size_t)srow * C1 + skc);

  for (int kk = 0; kk < 8; kk++) {
    __syncthreads();
    *(bf16x8*)(Al + srow * 32 + skc)        = va0;
    *(bf16x8*)(Al + (srow + 64) * 32 + skc) = va1;
    *(bf16x8*)(Bl + srow * 32 + skc)        = vb;
    __syncthreads();
    if (kk + 1 < 8) {
      const int k0 = (kk + 1) * 32;
      va0 = *(const bf16x8*)(A + (size_t)ra0 * C1 + k0 + skc);
      va1 = *(const bf16x8*)(A + (size_t)ra1 * C1 + k0 + skc);
      vb  = *(const bf16x8*)(Bt + (size_t)srow * C1 + k0 + skc);
    }
    bf16x8 af[4], bfr[2];
#pragma unroll
    for (int mi = 0; mi < 4; mi++)
      af[mi] = *(const bf16x8*)(Al + (wr + mi * 16 + lm) * 32 + q * 8);
#pragma unroll
    for (int ni = 0; ni < 2; ni++)
      bfr[ni] = *(const bf16x8*)(Bl + (wc + ni * 16 + lm) * 32 + q * 8);
#pragma unroll
    for (int mi = 0; mi < 4; mi++)
#pragma unroll
      for (int ni = 0; ni < 2; ni++)
        acc[mi][ni] = __builtin_amdgcn_mfma_f32_16x16x32_bf16(af[mi], bfr[ni], acc[mi][ni], 0, 0, 0);
  }

#pragma unroll
  for (int mi = 0; mi < 4; mi++) {
#pragma unroll
    for (int ni = 0; ni < 2; ni++) {
      const int col = wc + ni * 16 + lm;
#pragma unroll
      for (int r = 0; r < 4; r++) {
        const int row = bm + wr + mi * 16 + q * 4 + r;
        if (row < M) C[(size_t)row * CLS + col] = (__bf16)acc[mi][ni][r];
      }
    }
  }
}

// ---------------- attention score dots ----------------
__global__ __launch_bounds__(256) void att_scores1(const __bf16* __restrict__ h1,
    const float* __restrict__ asw, const float* __restrict__ adw,
    float* __restrict__ a_src, float* __restrict__ a_dst, int N) {
  const int t = threadIdx.x, lane = t & 63;
  const int n = blockIdx.x * 4 + (t >> 6);
  if (n >= N) return;
  bf16x4 x = *(const bf16x4*)(h1 + (size_t)n * C1 + lane * 4);
  const float4 wsv = *(const float4*)(asw + lane * 4);
  const float4 wdv = *(const float4*)(adw + lane * 4);
  float ps = (float)x[0] * wsv.x + (float)x[1] * wsv.y + (float)x[2] * wsv.z + (float)x[3] * wsv.w;
  float pd = (float)x[0] * wdv.x + (float)x[1] * wdv.y + (float)x[2] * wdv.z + (float)x[3] * wdv.w;
#pragma unroll
  for (int o = 1; o <= 4; o <<= 1) { ps += __shfl_xor(ps, o); pd += __shfl_xor(pd, o); }
  if ((lane & 7) == 0) {
    a_src[(size_t)n * 8 + (lane >> 3)] = ps;
    a_dst[(size_t)n * 8 + (lane >> 3)] = pd;
  }
}

__global__ __launch_bounds__(256) void att_scores2(const __bf16* __restrict__ h2b,
    const float* __restrict__ asw, const float* __restrict__ adw,
    float* __restrict__ a_src, float* __restrict__ a_dst, int N) {
  const int t = threadIdx.x, lane = t & 63;
  const int n = blockIdx.x * 4 + (t >> 6);
  if (n >= N) return;
  float v  = (float)h2b[(size_t)n * CLS + lane];
  float ps = v * asw[lane];
  float pd = v * adw[lane];
#pragma unroll
  for (int o = 1; o < 64; o <<= 1) { ps += __shfl_xor(ps, o); pd += __shfl_xor(pd, o); }
  if (lane == 0) { a_src[n] = ps; a_dst[n] = pd; }
}

// ---------------- CSR build (dst-indexed; self-loops implicit) ----------------
__global__ __launch_bounds__(256) void count_deg(const int* __restrict__ ei,
    int* __restrict__ deg, int E) {
  int e = blockIdx.x * 256 + threadIdx.x;
  if (e < E) atomicAdd(&deg[ei[E + e]], 1);
}

__global__ __launch_bounds__(1024) void scan_rows(const int* __restrict__ deg,
    int* __restrict__ rowstart, int N) {
  __shared__ int wpart[16];
  __shared__ int s_carry;
  const int t = threadIdx.x, lane = t & 63, wid = t >> 6;
  if (t == 0) s_carry = 0;
  __syncthreads();
  for (int base = 0; base < N; base += 8192) {
    int i0 = base + t * 8;
    int d0[8], s8 = 0;
#pragma unroll
    for (int k = 0; k < 8; k++) { int i = i0 + k; d0[k] = (i < N) ? deg[i] : 0; s8 += d0[k]; }
    int v = s8;
#pragma unroll
    for (int off = 1; off < 64; off <<= 1) { int x = __shfl_up(v, off); if (lane >= off) v += x; }
    if (lane == 63) wpart[wid] = v;
    __syncthreads();
    if (wid == 0) {
      int w = (lane < 16) ? wpart[lane] : 0;
#pragma unroll
      for (int off = 1; off < 16; off <<= 1) { int x = __shfl_up(w, off); if (lane >= off) w += x; }
      if (lane < 16) wpart[lane] = w;
    }
    __syncthreads();
    int excl = s_carry + (wid > 0 ? wpart[wid - 1] : 0) + v - s8;
#pragma unroll
    for (int k = 0; k < 8; k++) { int i = i0 + k; if (i < N) rowstart[i] = excl; excl += d0[k]; }
    __syncthreads();
    if (t == 0) s_carry += wpart[15];
    __syncthreads();
  }
  if (t == 0) rowstart[N] = s_carry;
}

__global__ __launch_bounds__(256) void scatter_csr(const int* __restrict__ ei,
    int* __restrict__ cur, int* __restrict__ csr_src, int E) {
  int e = blockIdx.x * 256 + threadIdx.x;
  if (e >= E) return;
  int s = ei[e], d = ei[E + e];
  int pos = atomicAdd(&cur[d], 1);
  csr_src[pos] = s;
}

// ---------------- layer-1 gather: wave per node, full 512B rows, 16B/lane ----------------
// score lanes: (e8 = lane>>3, hh = lane&7) -> 64 edges cached in se[8]/al[8]
// agg lanes:   (p = lane>>5 edge parity, g = lane&31 -> channels 8g..8g+7, head hg = g>>2)
__global__ __launch_bounds__(256) void gather1(const int* __restrict__ rowstart,
    const int* __restrict__ csr_src, const __bf16* __restrict__ h1,
    const float* __restrict__ as1, const float* __restrict__ ad1,
    const float* __restrict__ b1, __bf16* __restrict__ o1, int N) {
  const int t = threadIdx.x;
  const int d = blockIdx.x * 4 + (t >> 6);
  if (d >= N) return;
  const int lane = t & 63;
  const int e8 = lane >> 3, hh = lane & 7;
  const int r0 = rowstart[d];
  const int deg = rowstart[d + 1] - r0;

  const float addh = ad1[(size_t)d * 8 + hh];
  const float self_sc = leaky(as1[(size_t)d * 8 + hh] + addh);

  // --- scores for first 64 edges (registers) ---
  int   se[8];
  float sc[8];
#pragma unroll
  for (int ch = 0; ch < 8; ch++) {
    const int j = ch * 8 + e8;
    se[ch] = 0; sc[ch] = -3.4e38f;
    if (j < deg) {
      int s = csr_src[r0 + j];
      se[ch] = s;
      sc[ch] = leaky(as1[(size_t)s * 8 + hh] + addh);
    }
  }
  float mx = -3.4e38f;
#pragma unroll
  for (int ch = 0; ch < 8; ch++) mx = fmaxf(mx, sc[ch]);
  for (int j0 = 64; j0 < deg; j0 += 8) {     // rare tail
    int j = j0 + e8;
    if (j < deg) {
      int s = csr_src[r0 + j];
      mx = fmaxf(mx, leaky(as1[(size_t)s * 8 + hh] + addh));
    }
  }
  mx = fmaxf(mx, __shfl_xor(mx, 8));
  mx = fmaxf(mx, __shfl_xor(mx, 16));
  mx = fmaxf(mx, __shfl_xor(mx, 32));
  mx = fmaxf(mx, self_sc);

  float sum = 0.f;
#pragma unroll
  for (int ch = 0; ch < 8; ch++)
    if (ch * 8 + e8 < deg) sum += __expf(sc[ch] - mx);
  for (int j0 = 64; j0 < deg; j0 += 8) {
    int j = j0 + e8;
    if (j < deg) {
      int s = csr_src[r0 + j];
      sum += __expf(leaky(as1[(size_t)s * 8 + hh] + addh) - mx);
    }
  }
  sum += __shfl_xor(sum, 8);
  sum += __shfl_xor(sum, 16);
  sum += __shfl_xor(sum, 32);
  sum += __expf(self_sc - mx);
  const float inv = 1.f / (sum + EPS);

  float al[8];
#pragma unroll
  for (int ch = 0; ch < 8; ch++) al[ch] = __expf(sc[ch] - mx) * inv;   // 0 for pad lanes
  const float al_self_byhh = __expf(self_sc - mx) * inv;

  // --- aggregation: 2 edges per pass, 16B bf16x8 loads ---
  const int p = lane >> 5, g = lane & 31, hg = g >> 2;
  float acc[8];
#pragma unroll
  for (int i = 0; i < 8; i++) acc[i] = 0.f;

#pragma unroll
  for (int it = 0; it < 32; it++) {
    if (it * 2 < deg) {                        // wave-uniform
      const int   j   = it * 2 + p;            // al index (it*2)>>3 == (it*2+1)>>3
      const int   s_j = __shfl(se[it >> 2], (j & 7) * 8);
      const float a_j = __shfl(al[it >> 2], (j & 7) * 8 + hg);   // 0 if j>=deg
      bf16x8 x = *(const bf16x8*)(h1 + (size_t)s_j * C1 + g * 8);
#pragma unroll
      for (int i = 0; i < 8; i++) acc[i] += a_j * (float)x[i];
    }
  }
  // rare tail (deg > 64): 8 edges per chunk, scores at (e8,hh) layout
  for (int j0 = 64; j0 < deg; j0 += 8) {
    int j = j0 + e8;
    int se2 = 0; float al2 = 0.f;
    if (j < deg) { se2 = csr_src[r0 + j]; al2 = __expf(leaky(as1[(size_t)se2 * 8 + hh] + addh) - mx) * inv; }
#pragma unroll
    for (int it = 0; it < 4; it++) {
      if (j0 + it * 2 < deg) {
        const int   jj  = it * 2 + p;
        const int   s_j = __shfl(se2, jj * 8);
        const float a_j = __shfl(al2, jj * 8 + hg);
        bf16x8 x = *(const bf16x8*)(h1 + (size_t)s_j * C1 + g * 8);
#pragma unroll
        for (int i = 0; i < 8; i++) acc[i] += a_j * (float)x[i];
      }
    }
  }
#pragma unroll
  for (int i = 0; i < 8; i++) acc[i] += __shfl_xor(acc[i], 32);

  const float a_selfh = __shfl(al_self_byhh, hg);
  if (lane < 32) {
    bf16x8 xs = *(const bf16x8*)(h1 + (size_t)d * C1 + g * 8);
    const float4 b4a = *(const float4*)(b1 + g * 8);
    const float4 b4b = *(const float4*)(b1 + g * 8 + 4);
    bf16x8 o;
    o[0] = (__bf16)fmaxf(acc[0] + a_selfh * (float)xs[0] + b4a.x, 0.f);
    o[1] = (__bf16)fmaxf(acc[1] + a_selfh * (float)xs[1] + b4a.y, 0.f);
    o[2] = (__bf16)fmaxf(acc[2] + a_selfh * (float)xs[2] + b4a.z, 0.f);
    o[3] = (__bf16)fmaxf(acc[3] + a_selfh * (float)xs[3] + b4a.w, 0.f);
    o[4] = (__bf16)fmaxf(acc[4] + a_selfh * (float)xs[4] + b4b.x, 0.f);
    o[5] = (__bf16)fmaxf(acc[5] + a_selfh * (float)xs[5] + b4b.y, 0.f);
    o[6] = (__bf16)fmaxf(acc[6] + a_selfh * (float)xs[6] + b4b.z, 0.f);
    o[7] = (__bf16)fmaxf(acc[7] + a_selfh * (float)xs[7] + b4b.w, 0.f);
    *(bf16x8*)(o1 + (size_t)d * C1 + g * 8) = o;
  }
}

// ---------------- layer-2 gather: wave per node, 8 edges/pass, 16B/lane ----------------
// score lanes: lane = edge. agg lanes: (e8 = lane>>3 edge, c8 = lane&7 -> channels 8c8..8c8+7)
// writes raw logits fp32; bias+log_softmax in final_lsm
__global__ __launch_bounds__(256) void gather2(const int* __restrict__ rowstart,
    const int* __restrict__ csr_src, const __bf16* __restrict__ h2b,
    const float* __restrict__ as2, const float* __restrict__ ad2,
    float* __restrict__ out, int N) {
  const int t = threadIdx.x, lane = t & 63;
  const int d = blockIdx.x * 4 + (t >> 6);
  if (d >= N) return;
  const int r0 = rowstart[d], deg = rowstart[d + 1] - r0;
  const float addd = ad2[d];
  const float self_sc = leaky(as2[d] + addd);

  int se = 0; float sc = -3.4e38f;
  if (lane < deg) { se = csr_src[r0 + lane]; sc = leaky(as2[se] + addd); }
  float mx = sc;
  for (int j0 = 64; j0 < deg; j0 += 64) {
    int j = j0 + lane;
    if (j < deg) mx = fmaxf(mx, leaky(as2[csr_src[r0 + j]] + addd));
  }
#pragma unroll
  for (int o = 1; o < 64; o <<= 1) mx = fmaxf(mx, __shfl_xor(mx, o));
  mx = fmaxf(mx, self_sc);

  float ex = (lane < deg) ? __expf(sc - mx) : 0.f;
  float sum = ex;
  for (int j0 = 64; j0 < deg; j0 += 64) {
    int j = j0 + lane;
    if (j < deg) sum += __expf(leaky(as2[csr_src[r0 + j]] + addd) - mx);
  }
#pragma unroll
  for (int o = 1; o < 64; o <<= 1) sum += __shfl_xor(sum, o);
  const float e_self = __expf(self_sc - mx);
  sum += e_self;
  const float inv = 1.f / (sum + EPS);
  const float alpha = ex * inv;       // 0 for pad lanes
  const float al_self = e_self * inv;

  const int e8 = lane >> 3, c8 = lane & 7;
  float acc[8];
#pragma unroll
  for (int i = 0; i < 8; i++) acc[i] = 0.f;

#pragma unroll
  for (int it = 0; it < 8; it++) {
    if (it * 8 < deg) {                  // wave-uniform
      const int   j   = it * 8 + e8;
      const int   s_j = __shfl(se, j);
      const float a_j = __shfl(alpha, j);
      bf16x8 x = *(const bf16x8*)(h2b + (size_t)s_j * CLS + c8 * 8);
#pragma unroll
      for (int i = 0; i < 8; i++) acc[i] += a_j * (float)x[i];
    }
  }
  for (int j0 = 64; j0 < deg; j0 += 64) {   // rare tail
    int j = j0 + lane;
    int se2 = 0; float al2 = 0.f;
    if (j < deg) { se2 = csr_src[r0 + j]; al2 = __expf(leaky(as2[se2] + addd) - mx) * inv; }
#pragma unroll
    for (int it = 0; it < 8; it++) {
      if (j0 + it * 8 < deg) {
        const int   jj  = it * 8 + e8;
        const int   s_j = __shfl(se2, jj);
        const float a_j = __shfl(al2, jj);
        bf16x8 x = *(const bf16x8*)(h2b + (size_t)s_j * CLS + c8 * 8);
#pragma unroll
        for (int i = 0; i < 8; i++) acc[i] += a_j * (float)x[i];
      }
    }
  }
#pragma unroll
  for (int i = 0; i < 8; i++) {
    acc[i] += __shfl_xor(acc[i], 8);
    acc[i] += __shfl_xor(acc[i], 16);
    acc[i] += __shfl_xor(acc[i], 32);
  }
  if (lane < 8) {
    bf16x8 xs = *(const bf16x8*)(h2b + (size_t)d * CLS + c8 * 8);
    float4 o0, o1v;
    o0.x  = acc[0] + al_self * (float)xs[0];
    o0.y  = acc[1] + al_self * (float)xs[1];
    o0.z  = acc[2] + al_self * (float)xs[2];
    o0.w  = acc[3] + al_self * (float)xs[3];
    o1v.x = acc[4] + al_self * (float)xs[4];
    o1v.y = acc[5] + al_self * (float)xs[5];
    o1v.z = acc[6] + al_self * (float)xs[6];
    o1v.w = acc[7] + al_self * (float)xs[7];
    *(float4*)(out + (size_t)d * CLS + c8 * 8)     = o0;
    *(float4*)(out + (size_t)d * CLS + c8 * 8 + 4) = o1v;
  }
}

// ---------------- final: out = log_softmax(out + b2) in place; 4 nodes/block ----------------
__global__ __launch_bounds__(256) void final_lsm(float* __restrict__ out,
    const float* __restrict__ b2, int N) {
  const int t = threadIdx.x, c = t & 63;
  const int n = blockIdx.x * 4 + (t >> 6);
  if (n >= N) return;
  float v = out[(size_t)n * CLS + c] + b2[c];
  float mx = v;
#pragma unroll
  for (int o = 1; o < 64; o <<= 1) mx = fmaxf(mx, __shfl_xor(mx, o));
  float ex = __expf(v - mx);
  float sm = ex;
#pragma unroll
  for (int o = 1; o < 64; o <<= 1) sm += __shfl_xor(sm, o);
  out[(size_t)n * CLS + c] = v - mx - __logf(sm);
}

extern "C" void kernel_launch(void* const* d_in, const int* in_sizes, int n_in,
                              void* d_out, int out_size, void* d_ws, size_t ws_size,
                              hipStream_t stream) {
  const float* x        = (const float*)d_in[0];
  const int*   ei       = (const int*)d_in[1];
  const float* W1       = (const float*)d_in[2];
  const float* att_src1 = (const float*)d_in[3];
  const float* att_dst1 = (const float*)d_in[4];
  const float* b1       = (const float*)d_in[5];
  const float* W2       = (const float*)d_in[6];
  const float* att_src2 = (const float*)d_in[7];
  const float* att_dst2 = (const float*)d_in[8];
  const float* b2       = (const float*)d_in[9];
  float* out = (float*)d_out;

  const int N  = in_sizes[0] / F_IN;   // 50000
  const int E  = in_sizes[1] / 2;      // 800000

  char* ws = (char*)d_ws;
  size_t off = 0;
  auto alloc = [&](size_t bytes) -> void* {
    void* p = ws + off;
    off += (bytes + 255) & ~(size_t)255;
    return p;
  };
  __bf16* h1  = (__bf16*)alloc((size_t)N * C1 * 2);
  __bf16* o1  = (__bf16*)alloc((size_t)N * C1 * 2);
  float*  as1 = (float*)alloc((size_t)N * HEADS * 4);
  float*  ad1 = (float*)alloc((size_t)N * HEADS * 4);
  __bf16* h2b = (__bf16*)alloc((size_t)N * CLS * 2);
  float*  as2 = (float*)alloc((size_t)N * 4);
  float*  ad2 = (float*)alloc((size_t)N * 4);
  int* deg      = (int*)alloc((size_t)N * 4);
  int* rowstart = (int*)alloc((size_t)(N + 1) * 4);
  int* cur      = (int*)alloc((size_t)N * 4);
  int* csr_src  = (int*)alloc((size_t)E * 4);
  __bf16* xb  = (__bf16*)alloc((size_t)N * F_IN * 2);
  __bf16* w1t = (__bf16*)alloc((size_t)C1 * F_IN * 2);
  __bf16* w2t = (__bf16*)alloc((size_t)CLS * C1 * 2);

  // ---- bf16 conversions ----
  cvt_x<<<(N * F_IN / 8 + 255) / 256, 256, 0, stream>>>(x, xb, N * F_IN / 8);
  cvt_w1t<<<(C1 * F_IN / 8 + 255) / 256, 256, 0, stream>>>(W1, w1t);
  cvt_w2t<<<(CLS * C1 / 8 + 255) / 256, 256, 0, stream>>>(W2, w2t);

  // ---- CSR build (self-loops implicit in gather kernels) ----
  hipMemsetAsync(deg, 0, (size_t)N * 4, stream);
  count_deg<<<(E + 255) / 256, 256, 0, stream>>>(ei, deg, E);
  scan_rows<<<1, 1024, 0, stream>>>(deg, rowstart, N);
  hipMemcpyAsync(cur, rowstart, (size_t)N * 4, hipMemcpyDeviceToDevice, stream);
  scatter_csr<<<(E + 255) / 256, 256, 0, stream>>>(ei, cur, csr_src, E);

  // ---- layer 1 ----
  {
    dim3 g(C1 / 128, (N + 127) / 128);
    gemm1_mfma<<<g, 256, 0, stream>>>(xb, w1t, h1, N);
  }
  att_scores1<<<(N + 3) / 4, 256, 0, stream>>>(h1, att_src1, att_dst1, as1, ad1, N);
  gather1<<<(N + 3) / 4, 256, 0, stream>>>(rowstart, csr_src, h1, as1, ad1, b1, o1, N);

  // ---- layer 2 ----
  gemm2_mfma<<<(N + 127) / 128, 256, 0, stream>>>(o1, w2t, h2b, N);
  att_scores2<<<(N + 3) / 4, 256, 0, stream>>>(h2b, att_src2, att_dst2, as2, ad2, N);
  gather2<<<(N + 3) / 4, 256, 0, stream>>>(rowstart, csr_src, h2b, as2, ad2, out, N);

  // ---- bias + log_softmax ----
  final_lsm<<<(N + 3) / 4, 256, 0, stream>>>(out, b2, N);
}

// Round 8
// 414.895 us; speedup vs baseline: 1.5383x; 1.1604x over previous
//
#include <hip/hip_runtime.h>
#include <hip/hip_bf16.h>
#include <stdint.h>

#define F_IN 512
#define HID 32
#define HEADS 8
#define C1 (HEADS*HID)   // 256
#define CLS 64
#define NEG 0.2f
#define EPS 1e-16f

typedef __bf16 bf16x8 __attribute__((ext_vector_type(8)));
typedef __bf16 bf16x4 __attribute__((ext_vector_type(4)));
typedef float  f32x4  __attribute__((ext_vector_type(4)));

__device__ __forceinline__ float leaky(float v) { return v > 0.f ? v : NEG * v; }

__device__ __forceinline__ bf16x8 cvt8(float4 a, float4 b) {
  bf16x8 o;
  o[0] = (__bf16)a.x; o[1] = (__bf16)a.y; o[2] = (__bf16)a.z; o[3] = (__bf16)a.w;
  o[4] = (__bf16)b.x; o[5] = (__bf16)b.y; o[6] = (__bf16)b.z; o[7] = (__bf16)b.w;
  return o;
}

// ---------------- fused prep: cvt_w1t | cvt_w2t | count_deg ----------------
// blocks [0,64): W1[512][256] -> w1t[256][512] bf16
// blocks [64,72): W2[256][64] -> w2t[64][256] bf16
// blocks [72, 72+ceil(E/256)): deg histogram
__global__ __launch_bounds__(256) void prep(const float* __restrict__ W1,
    const float* __restrict__ W2, const int* __restrict__ ei,
    __bf16* __restrict__ w1t, __bf16* __restrict__ w2t,
    int* __restrict__ deg, int E) {
  const int b = blockIdx.x, t = threadIdx.x;
  if (b < 64) {
    int i = b * 256 + t;
    int o0 = i * 8;
    int c = o0 >> 9, k0 = o0 & 511;
    bf16x8 o;
#pragma unroll
    for (int j = 0; j < 8; j++) o[j] = (__bf16)W1[(size_t)(k0 + j) * C1 + c];
    *(bf16x8*)(w1t + (size_t)o0) = o;
  } else if (b < 72) {
    int i = (b - 64) * 256 + t;
    int o0 = i * 8;
    int c = o0 >> 8, k0 = o0 & 255;
    bf16x8 o;
#pragma unroll
    for (int j = 0; j < 8; j++) o[j] = (__bf16)W2[(size_t)(k0 + j) * CLS + c];
    *(bf16x8*)(w2t + (size_t)o0) = o;
  } else {
    int e = (b - 72) * 256 + t;
    if (e < E) atomicAdd(&deg[ei[E + e]], 1);
  }
}

// ---------------- parallel exclusive scan: deg[N] -> rowstart[N+1], cur[N] ----------------
__global__ __launch_bounds__(256) void scan_k1(const int* __restrict__ deg,
    int* __restrict__ bsum, int N) {
  __shared__ int ws[4];
  const int t = threadIdx.x, lane = t & 63, wid = t >> 6;
  int i = blockIdx.x * 256 + t;
  int v = (i < N) ? deg[i] : 0;
#pragma unroll
  for (int o = 1; o < 64; o <<= 1) v += __shfl_xor(v, o);
  if (lane == 0) ws[wid] = v;
  __syncthreads();
  if (t == 0) bsum[blockIdx.x] = ws[0] + ws[1] + ws[2] + ws[3];
}

__global__ __launch_bounds__(256) void scan_k2(int* __restrict__ bsum, int nb) {
  __shared__ int wsum[4];
  __shared__ int carry_s;
  const int t = threadIdx.x, lane = t & 63, wid = t >> 6;
  if (t == 0) carry_s = 0;
  __syncthreads();
  for (int base = 0; base < nb; base += 256) {
    int i = base + t;
    int v = (i < nb) ? bsum[i] : 0;
    int inc = v;
#pragma unroll
    for (int o = 1; o < 64; o <<= 1) { int x = __shfl_up(inc, o); if (lane >= o) inc += x; }
    if (lane == 63) wsum[wid] = inc;
    __syncthreads();
    int woff = 0;
    for (int w = 0; w < wid; w++) woff += wsum[w];
    int excl = carry_s + woff + inc - v;
    if (i < nb) bsum[i] = excl;
    __syncthreads();
    if (t == 0) carry_s += wsum[0] + wsum[1] + wsum[2] + wsum[3];
    __syncthreads();
  }
}

__global__ __launch_bounds__(256) void scan_k3(const int* __restrict__ deg,
    const int* __restrict__ bsum, int* __restrict__ rowstart,
    int* __restrict__ cur, int N) {
  __shared__ int wsum[4];
  const int t = threadIdx.x, lane = t & 63, wid = t >> 6;
  int i = blockIdx.x * 256 + t;
  int v = (i < N) ? deg[i] : 0;
  int inc = v;
#pragma unroll
  for (int o = 1; o < 64; o <<= 1) { int x = __shfl_up(inc, o); if (lane >= o) inc += x; }
  if (lane == 63) wsum[wid] = inc;
  __syncthreads();
  int woff = 0;
  for (int w = 0; w < wid; w++) woff += wsum[w];
  int excl = bsum[blockIdx.x] + woff + inc - v;
  if (i < N) { rowstart[i] = excl; cur[i] = excl; }
  if (i == N - 1) rowstart[N] = excl + v;
}

__global__ __launch_bounds__(256) void scatter_csr(const int* __restrict__ ei,
    int* __restrict__ cur, int* __restrict__ csr_src, int E) {
  int e = blockIdx.x * 256 + threadIdx.x;
  if (e >= E) return;
  int s = ei[e], d = ei[E + e];
  int pos = atomicAdd(&cur[d], 1);
  csr_src[pos] = s;
}

// ---------------- MFMA GEMM1: h1[M,256] = x[M,512](fp32, cast inline) @ w1t^T ----------------
__global__ __launch_bounds__(256) void gemm1_mfma(const float* __restrict__ A,
    const __bf16* __restrict__ Bt, __bf16* __restrict__ C, int M) {
  __shared__ __bf16 Al[128 * 32];
  __shared__ __bf16 Bl[128 * 32];
  const int tid  = threadIdx.x;
  const int lane = tid & 63;
  const int wave = tid >> 6;
  const int lm = lane & 15, q = lane >> 4;
  const int wr = (wave >> 1) * 64, wc = (wave & 1) * 64;
  const int bm = blockIdx.y * 128, bn = blockIdx.x * 128;

  const int srow = tid >> 2;
  const int skc  = (tid & 3) * 8;

  f32x4 acc[4][4];
#pragma unroll
  for (int i = 0; i < 4; i++)
#pragma unroll
    for (int j = 0; j < 4; j++) acc[i][j] = (f32x4){0.f, 0.f, 0.f, 0.f};

  const int ra0 = min(bm + srow, M - 1);
  const int ra1 = min(bm + srow + 64, M - 1);
  const int rb0 = bn + srow, rb1 = bn + srow + 64;

  float4 a0x, a0y, a1x, a1y;
  bf16x8 vb0, vb1;
  a0x = *(const float4*)(A + (size_t)ra0 * 512 + skc);
  a0y = *(const float4*)(A + (size_t)ra0 * 512 + skc + 4);
  a1x = *(const float4*)(A + (size_t)ra1 * 512 + skc);
  a1y = *(const float4*)(A + (size_t)ra1 * 512 + skc + 4);
  vb0 = *(const bf16x8*)(Bt + (size_t)rb0 * 512 + skc);
  vb1 = *(const bf16x8*)(Bt + (size_t)rb1 * 512 + skc);

  for (int kk = 0; kk < 16; kk++) {
    __syncthreads();
    *(bf16x8*)(Al + srow * 32 + skc)        = cvt8(a0x, a0y);
    *(bf16x8*)(Al + (srow + 64) * 32 + skc) = cvt8(a1x, a1y);
    *(bf16x8*)(Bl + srow * 32 + skc)        = vb0;
    *(bf16x8*)(Bl + (srow + 64) * 32 + skc) = vb1;
    __syncthreads();
    if (kk + 1 < 16) {
      const int k0 = (kk + 1) * 32;
      a0x = *(const float4*)(A + (size_t)ra0 * 512 + k0 + skc);
      a0y = *(const float4*)(A + (size_t)ra0 * 512 + k0 + skc + 4);
      a1x = *(const float4*)(A + (size_t)ra1 * 512 + k0 + skc);
      a1y = *(const float4*)(A + (size_t)ra1 * 512 + k0 + skc + 4);
      vb0 = *(const bf16x8*)(Bt + (size_t)rb0 * 512 + k0 + skc);
      vb1 = *(const bf16x8*)(Bt + (size_t)rb1 * 512 + k0 + skc);
    }
    bf16x8 af[4], bfr[4];
#pragma unroll
    for (int mi = 0; mi < 4; mi++)
      af[mi] = *(const bf16x8*)(Al + (wr + mi * 16 + lm) * 32 + q * 8);
#pragma unroll
    for (int ni = 0; ni < 4; ni++)
      bfr[ni] = *(const bf16x8*)(Bl + (wc + ni * 16 + lm) * 32 + q * 8);
#pragma unroll
    for (int mi = 0; mi < 4; mi++)
#pragma unroll
      for (int ni = 0; ni < 4; ni++)
        acc[mi][ni] = __builtin_amdgcn_mfma_f32_16x16x32_bf16(af[mi], bfr[ni], acc[mi][ni], 0, 0, 0);
  }

#pragma unroll
  for (int mi = 0; mi < 4; mi++) {
#pragma unroll
    for (int ni = 0; ni < 4; ni++) {
      const int col = bn + wc + ni * 16 + lm;
#pragma unroll
      for (int r = 0; r < 4; r++) {
        const int row = bm + wr + mi * 16 + q * 4 + r;
        if (row < M) C[(size_t)row * C1 + col] = (__bf16)acc[mi][ni][r];
      }
    }
  }
}

// ---------------- MFMA GEMM2: h2b[M,64](bf16) = o1[M,256] @ w2t^T ----------------
__global__ __launch_bounds__(256) void gemm2_mfma(const __bf16* __restrict__ A,
    const __bf16* __restrict__ Bt, __bf16* __restrict__ C, int M) {
  __shared__ __bf16 Al[128 * 32];
  __shared__ __bf16 Bl[64 * 32];
  const int tid  = threadIdx.x;
  const int lane = tid & 63;
  const int wave = tid >> 6;
  const int lm = lane & 15, q = lane >> 4;
  const int wr = (wave >> 1) * 64, wc = (wave & 1) * 32;
  const int bm = blockIdx.x * 128;

  const int srow = tid >> 2;
  const int skc  = (tid & 3) * 8;

  f32x4 acc[4][2];
#pragma unroll
  for (int i = 0; i < 4; i++)
#pragma unroll
    for (int j = 0; j < 2; j++) acc[i][j] = (f32x4){0.f, 0.f, 0.f, 0.f};

  const int ra0 = min(bm + srow, M - 1);
  const int ra1 = min(bm + srow + 64, M - 1);

  bf16x8 va0, va1, vb;
  va0 = *(const bf16x8*)(A + (size_t)ra0 * C1 + skc);
  va1 = *(const bf16x8*)(A + (size_t)ra1 * C1 + skc);
  vb  = *(const bf16x8*)(Bt + (size_t)srow * C1 + skc);

  for (int kk = 0; kk < 8; kk++) {
    __syncthreads();
    *(bf16x8*)(Al + srow * 32 + skc)        = va0;
    *(bf16x8*)(Al + (srow + 64) * 32 + skc) = va1;
    *(bf16x8*)(Bl + srow * 32 + skc)        = vb;
    __syncthreads();
    if (kk + 1 < 8) {
      const int k0 = (kk + 1) * 32;
      va0 = *(const bf16x8*)(A + (size_t)ra0 * C1 + k0 + skc);
      va1 = *(const bf16x8*)(A + (size_t)ra1 * C1 + k0 + skc);
      vb  = *(const bf16x8*)(Bt + (size_t)srow * C1 + k0 + skc);
    }
    bf16x8 af[4], bfr[2];
#pragma unroll
    for (int mi = 0; mi < 4; mi++)
      af[mi] = *(const bf16x8*)(Al + (wr + mi * 16 + lm) * 32 + q * 8);
#pragma unroll
    for (int ni = 0; ni < 2; ni++)
      bfr[ni] = *(const bf16x8*)(Bl + (wc + ni * 16 + lm) * 32 + q * 8);
#pragma unroll
    for (int mi = 0; mi < 4; mi++)
#pragma unroll
      for (int ni = 0; ni < 2; ni++)
        acc[mi][ni] = __builtin_amdgcn_mfma_f32_16x16x32_bf16(af[mi], bfr[ni], acc[mi][ni], 0, 0, 0);
  }

#pragma unroll
  for (int mi = 0; mi < 4; mi++) {
#pragma unroll
    for (int ni = 0; ni < 2; ni++) {
      const int col = wc + ni * 16 + lm;
#pragma unroll
      for (int r = 0; r < 4; r++) {
        const int row = bm + wr + mi * 16 + q * 4 + r;
        if (row < M) C[(size_t)row * CLS + col] = (__bf16)acc[mi][ni][r];
      }
    }
  }
}

// ---------------- attention score dots ----------------
__global__ __launch_bounds__(256) void att_scores1(const __bf16* __restrict__ h1,
    const float* __restrict__ asw, const float* __restrict__ adw,
    float* __restrict__ a_src, float* __restrict__ a_dst, int N) {
  const int t = threadIdx.x, lane = t & 63;
  const int n = blockIdx.x * 4 + (t >> 6);
  if (n >= N) return;
  bf16x4 x = *(const bf16x4*)(h1 + (size_t)n * C1 + lane * 4);
  const float4 wsv = *(const float4*)(asw + lane * 4);
  const float4 wdv = *(const float4*)(adw + lane * 4);
  float ps = (float)x[0] * wsv.x + (float)x[1] * wsv.y + (float)x[2] * wsv.z + (float)x[3] * wsv.w;
  float pd = (float)x[0] * wdv.x + (float)x[1] * wdv.y + (float)x[2] * wdv.z + (float)x[3] * wdv.w;
#pragma unroll
  for (int o = 1; o <= 4; o <<= 1) { ps += __shfl_xor(ps, o); pd += __shfl_xor(pd, o); }
  if ((lane & 7) == 0) {
    a_src[(size_t)n * 8 + (lane >> 3)] = ps;
    a_dst[(size_t)n * 8 + (lane >> 3)] = pd;
  }
}

__global__ __launch_bounds__(256) void att_scores2(const __bf16* __restrict__ h2b,
    const float* __restrict__ asw, const float* __restrict__ adw,
    float* __restrict__ a_src, float* __restrict__ a_dst, int N) {
  const int t = threadIdx.x, lane = t & 63;
  const int n = blockIdx.x * 4 + (t >> 6);
  if (n >= N) return;
  float v  = (float)h2b[(size_t)n * CLS + lane];
  float ps = v * asw[lane];
  float pd = v * adw[lane];
#pragma unroll
  for (int o = 1; o < 64; o <<= 1) { ps += __shfl_xor(ps, o); pd += __shfl_xor(pd, o); }
  if (lane == 0) { a_src[n] = ps; a_dst[n] = pd; }
}

// ---------------- layer-1 gather (unchanged from R6: 76µs, proven) ----------------
__global__ __launch_bounds__(256) void gather1(const int* __restrict__ rowstart,
    const int* __restrict__ csr_src, const __bf16* __restrict__ h1,
    const float* __restrict__ as1, const float* __restrict__ ad1,
    const float* __restrict__ b1, __bf16* __restrict__ o1, int N) {
  const int t = threadIdx.x;
  const int d = blockIdx.x * 4 + (t >> 6);
  if (d >= N) return;
  const int lane = t & 63;
  const int e8 = lane >> 3, hh = lane & 7;
  const int r0 = rowstart[d];
  const int deg = rowstart[d + 1] - r0;

  const float addh = ad1[(size_t)d * 8 + hh];
  const float self_sc = leaky(as1[(size_t)d * 8 + hh] + addh);

  int   se[8];
  float sc[8];
#pragma unroll
  for (int ch = 0; ch < 8; ch++) {
    const int j = ch * 8 + e8;
    se[ch] = 0; sc[ch] = -3.4e38f;
    if (j < deg) {
      int s = csr_src[r0 + j];
      se[ch] = s;
      sc[ch] = leaky(as1[(size_t)s * 8 + hh] + addh);
    }
  }
  float mx = -3.4e38f;
#pragma unroll
  for (int ch = 0; ch < 8; ch++) mx = fmaxf(mx, sc[ch]);
  for (int j0 = 64; j0 < deg; j0 += 8) {
    int j = j0 + e8;
    if (j < deg) {
      int s = csr_src[r0 + j];
      mx = fmaxf(mx, leaky(as1[(size_t)s * 8 + hh] + addh));
    }
  }
  mx = fmaxf(mx, __shfl_xor(mx, 8));
  mx = fmaxf(mx, __shfl_xor(mx, 16));
  mx = fmaxf(mx, __shfl_xor(mx, 32));
  mx = fmaxf(mx, self_sc);

  float sum = 0.f;
#pragma unroll
  for (int ch = 0; ch < 8; ch++)
    if (ch * 8 + e8 < deg) sum += __expf(sc[ch] - mx);
  for (int j0 = 64; j0 < deg; j0 += 8) {
    int j = j0 + e8;
    if (j < deg) {
      int s = csr_src[r0 + j];
      sum += __expf(leaky(as1[(size_t)s * 8 + hh] + addh) - mx);
    }
  }
  sum += __shfl_xor(sum, 8);
  sum += __shfl_xor(sum, 16);
  sum += __shfl_xor(sum, 32);
  sum += __expf(self_sc - mx);
  const float inv = 1.f / (sum + EPS);

  float al[8];
#pragma unroll
  for (int ch = 0; ch < 8; ch++) al[ch] = __expf(sc[ch] - mx) * inv;
  const float al_self_byhh = __expf(self_sc - mx) * inv;

  const int p = lane >> 5, g = lane & 31, hg = g >> 2;
  float acc[8];
#pragma unroll
  for (int i = 0; i < 8; i++) acc[i] = 0.f;

#pragma unroll
  for (int it = 0; it < 32; it++) {
    if (it * 2 < deg) {
      const int   j   = it * 2 + p;
      const int   s_j = __shfl(se[it >> 2], (j & 7) * 8);
      const float a_j = __shfl(al[it >> 2], (j & 7) * 8 + hg);
      bf16x8 x = *(const bf16x8*)(h1 + (size_t)s_j * C1 + g * 8);
#pragma unroll
      for (int i = 0; i < 8; i++) acc[i] += a_j * (float)x[i];
    }
  }
  for (int j0 = 64; j0 < deg; j0 += 8) {
    int j = j0 + e8;
    int se2 = 0; float al2 = 0.f;
    if (j < deg) { se2 = csr_src[r0 + j]; al2 = __expf(leaky(as1[(size_t)se2 * 8 + hh] + addh) - mx) * inv; }
#pragma unroll
    for (int it = 0; it < 4; it++) {
      if (j0 + it * 2 < deg) {
        const int   jj  = it * 2 + p;
        const int   s_j = __shfl(se2, jj * 8);
        const float a_j = __shfl(al2, jj * 8 + hg);
        bf16x8 x = *(const bf16x8*)(h1 + (size_t)s_j * C1 + g * 8);
#pragma unroll
        for (int i = 0; i < 8; i++) acc[i] += a_j * (float)x[i];
      }
    }
  }
#pragma unroll
  for (int i = 0; i < 8; i++) acc[i] += __shfl_xor(acc[i], 32);

  const float a_selfh = __shfl(al_self_byhh, hg);
  if (lane < 32) {
    bf16x8 xs = *(const bf16x8*)(h1 + (size_t)d * C1 + g * 8);
    const float4 b4a = *(const float4*)(b1 + g * 8);
    const float4 b4b = *(const float4*)(b1 + g * 8 + 4);
    bf16x8 o;
    o[0] = (__bf16)fmaxf(acc[0] + a_selfh * (float)xs[0] + b4a.x, 0.f);
    o[1] = (__bf16)fmaxf(acc[1] + a_selfh * (float)xs[1] + b4a.y, 0.f);
    o[2] = (__bf16)fmaxf(acc[2] + a_selfh * (float)xs[2] + b4a.z, 0.f);
    o[3] = (__bf16)fmaxf(acc[3] + a_selfh * (float)xs[3] + b4a.w, 0.f);
    o[4] = (__bf16)fmaxf(acc[4] + a_selfh * (float)xs[4] + b4b.x, 0.f);
    o[5] = (__bf16)fmaxf(acc[5] + a_selfh * (float)xs[5] + b4b.y, 0.f);
    o[6] = (__bf16)fmaxf(acc[6] + a_selfh * (float)xs[6] + b4b.z, 0.f);
    o[7] = (__bf16)fmaxf(acc[7] + a_selfh * (float)xs[7] + b4b.w, 0.f);
    *(bf16x8*)(o1 + (size_t)d * C1 + g * 8) = o;
  }
}

// ---------------- layer-2 gather + fused bias + log_softmax ----------------
__global__ __launch_bounds__(256) void gather2(const int* __restrict__ rowstart,
    const int* __restrict__ csr_src, const __bf16* __restrict__ h2b,
    const float* __restrict__ as2, const float* __restrict__ ad2,
    const float* __restrict__ b2, float* __restrict__ out, int N) {
  const int t = threadIdx.x, lane = t & 63;
  const int d = blockIdx.x * 4 + (t >> 6);
  if (d >= N) return;
  const int r0 = rowstart[d], deg = rowstart[d + 1] - r0;
  const float addd = ad2[d];
  const float self_sc = leaky(as2[d] + addd);

  int se = 0; float sc = -3.4e38f;
  if (lane < deg) { se = csr_src[r0 + lane]; sc = leaky(as2[se] + addd); }
  float mx = sc;
  for (int j0 = 64; j0 < deg; j0 += 64) {
    int j = j0 + lane;
    if (j < deg) mx = fmaxf(mx, leaky(as2[csr_src[r0 + j]] + addd));
  }
#pragma unroll
  for (int o = 1; o < 64; o <<= 1) mx = fmaxf(mx, __shfl_xor(mx, o));
  mx = fmaxf(mx, self_sc);

  float ex = (lane < deg) ? __expf(sc - mx) : 0.f;
  float sum = ex;
  for (int j0 = 64; j0 < deg; j0 += 64) {
    int j = j0 + lane;
    if (j < deg) sum += __expf(leaky(as2[csr_src[r0 + j]] + addd) - mx);
  }
#pragma unroll
  for (int o = 1; o < 64; o <<= 1) sum += __shfl_xor(sum, o);
  const float e_self = __expf(self_sc - mx);
  sum += e_self;
  const float inv = 1.f / (sum + EPS);
  const float alpha = ex * inv;
  const float al_self = e_self * inv;

  const int e8 = lane >> 3, c8 = lane & 7;
  float acc[8];
#pragma unroll
  for (int i = 0; i < 8; i++) acc[i] = 0.f;

#pragma unroll
  for (int it = 0; it < 8; it++) {
    if (it * 8 < deg) {
      const int   j   = it * 8 + e8;
      const int   s_j = __shfl(se, j);
      const float a_j = __shfl(alpha, j);
      bf16x8 x = *(const bf16x8*)(h2b + (size_t)s_j * CLS + c8 * 8);
#pragma unroll
      for (int i = 0; i < 8; i++) acc[i] += a_j * (float)x[i];
    }
  }
  for (int j0 = 64; j0 < deg; j0 += 64) {
    int j = j0 + lane;
    int se2 = 0; float al2 = 0.f;
    if (j < deg) { se2 = csr_src[r0 + j]; al2 = __expf(leaky(as2[se2] + addd) - mx) * inv; }
#pragma unroll
    for (int it = 0; it < 8; it++) {
      if (j0 + it * 8 < deg) {
        const int   jj  = it * 8 + e8;
        const int   s_j = __shfl(se2, jj);
        const float a_j = __shfl(al2, jj);
        bf16x8 x = *(const bf16x8*)(h2b + (size_t)s_j * CLS + c8 * 8);
#pragma unroll
        for (int i = 0; i < 8; i++) acc[i] += a_j * (float)x[i];
      }
    }
  }
#pragma unroll
  for (int i = 0; i < 8; i++) {
    acc[i] += __shfl_xor(acc[i], 8);
    acc[i] += __shfl_xor(acc[i], 16);
    acc[i] += __shfl_xor(acc[i], 32);
  }

  // fused self-add + bias + log_softmax (row lives across lanes' c8 slots)
  bf16x8 xs = *(const bf16x8*)(h2b + (size_t)d * CLS + c8 * 8);
  const float4 bba = *(const float4*)(b2 + c8 * 8);
  const float4 bbb = *(const float4*)(b2 + c8 * 8 + 4);
  float v[8];
  v[0] = acc[0] + al_self * (float)xs[0] + bba.x;
  v[1] = acc[1] + al_self * (float)xs[1] + bba.y;
  v[2] = acc[2] + al_self * (float)xs[2] + bba.z;
  v[3] = acc[3] + al_self * (float)xs[3] + bba.w;
  v[4] = acc[4] + al_self * (float)xs[4] + bbb.x;
  v[5] = acc[5] + al_self * (float)xs[5] + bbb.y;
  v[6] = acc[6] + al_self * (float)xs[6] + bbb.z;
  v[7] = acc[7] + al_self * (float)xs[7] + bbb.w;
  float m2 = v[0];
#pragma unroll
  for (int i = 1; i < 8; i++) m2 = fmaxf(m2, v[i]);
  m2 = fmaxf(m2, __shfl_xor(m2, 1));
  m2 = fmaxf(m2, __shfl_xor(m2, 2));
  m2 = fmaxf(m2, __shfl_xor(m2, 4));
  float sm = 0.f;
#pragma unroll
  for (int i = 0; i < 8; i++) sm += __expf(v[i] - m2);
  sm += __shfl_xor(sm, 1);
  sm += __shfl_xor(sm, 2);
  sm += __shfl_xor(sm, 4);
  const float lg = m2 + __logf(sm);
  if (lane < 8) {
    float4 o0, o1v;
    o0.x  = v[0] - lg; o0.y  = v[1] - lg; o0.z  = v[2] - lg; o0.w  = v[3] - lg;
    o1v.x = v[4] - lg; o1v.y = v[5] - lg; o1v.z = v[6] - lg; o1v.w = v[7] - lg;
    *(float4*)(out + (size_t)d * CLS + c8 * 8)     = o0;
    *(float4*)(out + (size_t)d * CLS + c8 * 8 + 4) = o1v;
  }
}

extern "C" void kernel_launch(void* const* d_in, const int* in_sizes, int n_in,
                              void* d_out, int out_size, void* d_ws, size_t ws_size,
                              hipStream_t stream) {
  const float* x        = (const float*)d_in[0];
  const int*   ei       = (const int*)d_in[1];
  const float* W1       = (const float*)d_in[2];
  const float* att_src1 = (const float*)d_in[3];
  const float* att_dst1 = (const float*)d_in[4];
  const float* b1       = (const float*)d_in[5];
  const float* W2       = (const float*)d_in[6];
  const float* att_src2 = (const float*)d_in[7];
  const float* att_dst2 = (const float*)d_in[8];
  const float* b2       = (const float*)d_in[9];
  float* out = (float*)d_out;

  const int N  = in_sizes[0] / F_IN;   // 50000
  const int E  = in_sizes[1] / 2;      // 800000
  const int NB = (N + 255) / 256;      // scan blocks

  char* ws = (char*)d_ws;
  size_t off = 0;
  auto alloc = [&](size_t bytes) -> void* {
    void* p = ws + off;
    off += (bytes + 255) & ~(size_t)255;
    return p;
  };
  __bf16* h1  = (__bf16*)alloc((size_t)N * C1 * 2);
  __bf16* o1  = (__bf16*)alloc((size_t)N * C1 * 2);
  float*  as1 = (float*)alloc((size_t)N * HEADS * 4);
  float*  ad1 = (float*)alloc((size_t)N * HEADS * 4);
  __bf16* h2b = (__bf16*)alloc((size_t)N * CLS * 2);
  float*  as2 = (float*)alloc((size_t)N * 4);
  float*  ad2 = (float*)alloc((size_t)N * 4);
  int* deg      = (int*)alloc((size_t)N * 4);
  int* rowstart = (int*)alloc((size_t)(N + 1) * 4);
  int* cur      = (int*)alloc((size_t)N * 4);
  int* csr_src  = (int*)alloc((size_t)E * 4);
  int* bsum     = (int*)alloc((size_t)NB * 4);
  __bf16* w1t = (__bf16*)alloc((size_t)C1 * F_IN * 2);
  __bf16* w2t = (__bf16*)alloc((size_t)CLS * C1 * 2);

  // ---- prep: weight casts + degree histogram ----
  hipMemsetAsync(deg, 0, (size_t)N * 4, stream);
  prep<<<72 + (E + 255) / 256, 256, 0, stream>>>(W1, W2, ei, w1t, w2t, deg, E);

  // ---- parallel scan -> rowstart, cur ----
  scan_k1<<<NB, 256, 0, stream>>>(deg, bsum, N);
  scan_k2<<<1, 256, 0, stream>>>(bsum, NB);
  scan_k3<<<NB, 256, 0, stream>>>(deg, bsum, rowstart, cur, N);
  scatter_csr<<<(E + 255) / 256, 256, 0, stream>>>(ei, cur, csr_src, E);

  // ---- layer 1 ----
  {
    dim3 g(C1 / 128, (N + 127) / 128);
    gemm1_mfma<<<g, 256, 0, stream>>>(x, w1t, h1, N);
  }
  att_scores1<<<(N + 3) / 4, 256, 0, stream>>>(h1, att_src1, att_dst1, as1, ad1, N);
  gather1<<<(N + 3) / 4, 256, 0, stream>>>(rowstart, csr_src, h1, as1, ad1, b1, o1, N);

  // ---- layer 2 ----
  gemm2_mfma<<<(N + 127) / 128, 256, 0, stream>>>(o1, w2t, h2b, N);
  att_scores2<<<(N + 3) / 4, 256, 0, stream>>>(h2b, att_src2, att_dst2, as2, ad2, N);
  gather2<<<(N + 3) / 4, 256, 0, stream>>>(rowstart, csr_src, h2b, as2, ad2, b2, out, N);
}

// Round 9
// 412.960 us; speedup vs baseline: 1.5455x; 1.0047x over previous
//
#include <hip/hip_runtime.h>
#include <hip/hip_bf16.h>
#include <stdint.h>

#define F_IN 512
#define HID 32
#define HEADS 8
#define C1 (HEADS*HID)   // 256
#define CLS 64
#define NEG 0.2f
#define EPS 1e-16f

typedef __bf16 bf16x8 __attribute__((ext_vector_type(8)));
typedef __bf16 bf16x4 __attribute__((ext_vector_type(4)));
typedef float  f32x4  __attribute__((ext_vector_type(4)));

__device__ __forceinline__ float leaky(float v) { return v > 0.f ? v : NEG * v; }

__device__ __forceinline__ bf16x8 cvt8(float4 a, float4 b) {
  bf16x8 o;
  o[0] = (__bf16)a.x; o[1] = (__bf16)a.y; o[2] = (__bf16)a.z; o[3] = (__bf16)a.w;
  o[4] = (__bf16)b.x; o[5] = (__bf16)b.y; o[6] = (__bf16)b.z; o[7] = (__bf16)b.w;
  return o;
}

// ---------------- fused prep: cvt_w1t | cvt_w2t | count_deg ----------------
__global__ __launch_bounds__(256) void prep(const float* __restrict__ W1,
    const float* __restrict__ W2, const int* __restrict__ ei,
    __bf16* __restrict__ w1t, __bf16* __restrict__ w2t,
    int* __restrict__ deg, int E) {
  const int b = blockIdx.x, t = threadIdx.x;
  if (b < 64) {
    int i = b * 256 + t;
    int o0 = i * 8;
    int c = o0 >> 9, k0 = o0 & 511;
    bf16x8 o;
#pragma unroll
    for (int j = 0; j < 8; j++) o[j] = (__bf16)W1[(size_t)(k0 + j) * C1 + c];
    *(bf16x8*)(w1t + (size_t)o0) = o;
  } else if (b < 72) {
    int i = (b - 64) * 256 + t;
    int o0 = i * 8;
    int c = o0 >> 8, k0 = o0 & 255;
    bf16x8 o;
#pragma unroll
    for (int j = 0; j < 8; j++) o[j] = (__bf16)W2[(size_t)(k0 + j) * CLS + c];
    *(bf16x8*)(w2t + (size_t)o0) = o;
  } else {
    int e = (b - 72) * 256 + t;
    if (e < E) atomicAdd(&deg[ei[E + e]], 1);
  }
}

// ---------------- parallel exclusive scan ----------------
__global__ __launch_bounds__(256) void scan_k1(const int* __restrict__ deg,
    int* __restrict__ bsum, int N) {
  __shared__ int ws[4];
  const int t = threadIdx.x, lane = t & 63, wid = t >> 6;
  int i = blockIdx.x * 256 + t;
  int v = (i < N) ? deg[i] : 0;
#pragma unroll
  for (int o = 1; o < 64; o <<= 1) v += __shfl_xor(v, o);
  if (lane == 0) ws[wid] = v;
  __syncthreads();
  if (t == 0) bsum[blockIdx.x] = ws[0] + ws[1] + ws[2] + ws[3];
}

__global__ __launch_bounds__(256) void scan_k2(int* __restrict__ bsum, int nb) {
  __shared__ int wsum[4];
  __shared__ int carry_s;
  const int t = threadIdx.x, lane = t & 63, wid = t >> 6;
  if (t == 0) carry_s = 0;
  __syncthreads();
  for (int base = 0; base < nb; base += 256) {
    int i = base + t;
    int v = (i < nb) ? bsum[i] : 0;
    int inc = v;
#pragma unroll
    for (int o = 1; o < 64; o <<= 1) { int x = __shfl_up(inc, o); if (lane >= o) inc += x; }
    if (lane == 63) wsum[wid] = inc;
    __syncthreads();
    int woff = 0;
    for (int w = 0; w < wid; w++) woff += wsum[w];
    int excl = carry_s + woff + inc - v;
    if (i < nb) bsum[i] = excl;
    __syncthreads();
    if (t == 0) carry_s += wsum[0] + wsum[1] + wsum[2] + wsum[3];
    __syncthreads();
  }
}

__global__ __launch_bounds__(256) void scan_k3(const int* __restrict__ deg,
    const int* __restrict__ bsum, int* __restrict__ rowstart,
    int* __restrict__ cur, int N) {
  __shared__ int wsum[4];
  const int t = threadIdx.x, lane = t & 63, wid = t >> 6;
  int i = blockIdx.x * 256 + t;
  int v = (i < N) ? deg[i] : 0;
  int inc = v;
#pragma unroll
  for (int o = 1; o < 64; o <<= 1) { int x = __shfl_up(inc, o); if (lane >= o) inc += x; }
  if (lane == 63) wsum[wid] = inc;
  __syncthreads();
  int woff = 0;
  for (int w = 0; w < wid; w++) woff += wsum[w];
  int excl = bsum[blockIdx.x] + woff + inc - v;
  if (i < N) { rowstart[i] = excl; cur[i] = excl; }
  if (i == N - 1) rowstart[N] = excl + v;
}

__global__ __launch_bounds__(256) void scatter_csr(const int* __restrict__ ei,
    int* __restrict__ cur, int* __restrict__ csr_src, int E) {
  int e = blockIdx.x * 256 + threadIdx.x;
  if (e >= E) return;
  int s = ei[e], d = ei[E + e];
  int pos = atomicAdd(&cur[d], 1);
  csr_src[pos] = s;
}

// ---------------- GEMM1 fused: h1 = x @ w1t^T (BN=256 full width) + att scores 1 ----------------
// block = 128 rows x 256 cols; 4 waves, each owns two 64x64 wave tiles (wc0, wc0+128)
__global__ __launch_bounds__(256) void gemm1_fused(const float* __restrict__ A,
    const __bf16* __restrict__ Bt, __bf16* __restrict__ C,
    const float* __restrict__ asw, const float* __restrict__ adw,
    float* __restrict__ a_src, float* __restrict__ a_dst, int M) {
  __shared__ __bf16 Al[128 * 32];
  __shared__ __bf16 Bl[256 * 32];
  const int tid = threadIdx.x, lane = tid & 63, wave = tid >> 6;
  const int lm = lane & 15, q = lane >> 4;
  const int wr = (wave >> 1) * 64, wc0 = (wave & 1) * 64;
  const int bm = blockIdx.x * 128;
  const int srow = tid >> 2, skc = (tid & 3) * 8;

  f32x4 acc[2][4][4];
#pragma unroll
  for (int hf = 0; hf < 2; hf++)
#pragma unroll
    for (int i = 0; i < 4; i++)
#pragma unroll
      for (int j = 0; j < 4; j++) acc[hf][i][j] = (f32x4){0.f, 0.f, 0.f, 0.f};

  const int ra0 = min(bm + srow, M - 1);
  const int ra1 = min(bm + srow + 64, M - 1);

  float4 a00, a01, a10, a11;
  bf16x8 vb[4];
  a00 = *(const float4*)(A + (size_t)ra0 * 512 + skc);
  a01 = *(const float4*)(A + (size_t)ra0 * 512 + skc + 4);
  a10 = *(const float4*)(A + (size_t)ra1 * 512 + skc);
  a11 = *(const float4*)(A + (size_t)ra1 * 512 + skc + 4);
#pragma unroll
  for (int rr = 0; rr < 4; rr++)
    vb[rr] = *(const bf16x8*)(Bt + (size_t)(srow + rr * 64) * 512 + skc);

  for (int kk = 0; kk < 16; kk++) {
    __syncthreads();
    *(bf16x8*)(Al + srow * 32 + skc)        = cvt8(a00, a01);
    *(bf16x8*)(Al + (srow + 64) * 32 + skc) = cvt8(a10, a11);
#pragma unroll
    for (int rr = 0; rr < 4; rr++)
      *(bf16x8*)(Bl + (srow + rr * 64) * 32 + skc) = vb[rr];
    __syncthreads();
    if (kk + 1 < 16) {
      const int k0 = (kk + 1) * 32;
      a00 = *(const float4*)(A + (size_t)ra0 * 512 + k0 + skc);
      a01 = *(const float4*)(A + (size_t)ra0 * 512 + k0 + skc + 4);
      a10 = *(const float4*)(A + (size_t)ra1 * 512 + k0 + skc);
      a11 = *(const float4*)(A + (size_t)ra1 * 512 + k0 + skc + 4);
#pragma unroll
      for (int rr = 0; rr < 4; rr++)
        vb[rr] = *(const bf16x8*)(Bt + (size_t)(srow + rr * 64) * 512 + k0 + skc);
    }
    bf16x8 af[4];
#pragma unroll
    for (int mi = 0; mi < 4; mi++)
      af[mi] = *(const bf16x8*)(Al + (wr + mi * 16 + lm) * 32 + q * 8);
#pragma unroll
    for (int hf = 0; hf < 2; hf++) {
      bf16x8 bfr[4];
#pragma unroll
      for (int ni = 0; ni < 4; ni++)
        bfr[ni] = *(const bf16x8*)(Bl + (wc0 + hf * 128 + ni * 16 + lm) * 32 + q * 8);
#pragma unroll
      for (int mi = 0; mi < 4; mi++)
#pragma unroll
        for (int ni = 0; ni < 4; ni++)
          acc[hf][mi][ni] = __builtin_amdgcn_mfma_f32_16x16x32_bf16(af[mi], bfr[ni], acc[hf][mi][ni], 0, 0, 0);
    }
  }

  // store h1 (bf16)
#pragma unroll
  for (int hf = 0; hf < 2; hf++) {
#pragma unroll
    for (int mi = 0; mi < 4; mi++) {
#pragma unroll
      for (int ni = 0; ni < 4; ni++) {
        const int col = wc0 + hf * 128 + ni * 16 + lm;
#pragma unroll
        for (int r = 0; r < 4; r++) {
          const int row = bm + wr + mi * 16 + q * 4 + r;
          if (row < M) C[(size_t)row * C1 + col] = (__bf16)acc[hf][mi][ni][r];
        }
      }
    }
  }

  // fused attention scores (from fp32 acc, pre-rounding)
#pragma unroll
  for (int hf = 0; hf < 2; hf++) {
    const int cb = wc0 + hf * 128;
    const int h0 = cb >> 5;                      // head pair h0, h0+1
    float ws[4], wd[4];
#pragma unroll
    for (int ni = 0; ni < 4; ni++) {
      ws[ni] = asw[cb + ni * 16 + lm];
      wd[ni] = adw[cb + ni * 16 + lm];
    }
#pragma unroll
    for (int mi = 0; mi < 4; mi++) {
#pragma unroll
      for (int r = 0; r < 4; r++) {
        float ps0 = acc[hf][mi][0][r] * ws[0] + acc[hf][mi][1][r] * ws[1];
        float ps1 = acc[hf][mi][2][r] * ws[2] + acc[hf][mi][3][r] * ws[3];
        float pd0 = acc[hf][mi][0][r] * wd[0] + acc[hf][mi][1][r] * wd[1];
        float pd1 = acc[hf][mi][2][r] * wd[2] + acc[hf][mi][3][r] * wd[3];
#pragma unroll
        for (int o = 1; o <= 8; o <<= 1) {
          ps0 += __shfl_xor(ps0, o); ps1 += __shfl_xor(ps1, o);
          pd0 += __shfl_xor(pd0, o); pd1 += __shfl_xor(pd1, o);
        }
        if (lm == 0) {
          const int row = bm + wr + mi * 16 + q * 4 + r;
          if (row < M) {
            a_src[(size_t)row * 8 + h0]     = ps0;
            a_src[(size_t)row * 8 + h0 + 1] = ps1;
            a_dst[(size_t)row * 8 + h0]     = pd0;
            a_dst[(size_t)row * 8 + h0 + 1] = pd1;
          }
        }
      }
    }
  }
}

// ---------------- GEMM2 fused: h2b = o1 @ w2t^T (bf16 out) + att scores 2 ----------------
__global__ __launch_bounds__(256) void gemm2_fused(const __bf16* __restrict__ A,
    const __bf16* __restrict__ Bt, __bf16* __restrict__ C,
    const float* __restrict__ asw, const float* __restrict__ adw,
    float* __restrict__ a_src, float* __restrict__ a_dst, int M) {
  __shared__ __bf16 Al[128 * 32];
  __shared__ __bf16 Bl[64 * 32];
  __shared__ float sred[128][2][2];   // [row_local][col half][src/dst]
  const int tid = threadIdx.x, lane = tid & 63, wave = tid >> 6;
  const int lm = lane & 15, q = lane >> 4;
  const int wr = (wave >> 1) * 64, wc = (wave & 1) * 32;
  const int bm = blockIdx.x * 128;
  const int srow = tid >> 2, skc = (tid & 3) * 8;

  f32x4 acc[4][2];
#pragma unroll
  for (int i = 0; i < 4; i++)
#pragma unroll
    for (int j = 0; j < 2; j++) acc[i][j] = (f32x4){0.f, 0.f, 0.f, 0.f};

  const int ra0 = min(bm + srow, M - 1);
  const int ra1 = min(bm + srow + 64, M - 1);

  bf16x8 va0, va1, vb;
  va0 = *(const bf16x8*)(A + (size_t)ra0 * C1 + skc);
  va1 = *(const bf16x8*)(A + (size_t)ra1 * C1 + skc);
  vb  = *(const bf16x8*)(Bt + (size_t)srow * C1 + skc);

  for (int kk = 0; kk < 8; kk++) {
    __syncthreads();
    *(bf16x8*)(Al + srow * 32 + skc)        = va0;
    *(bf16x8*)(Al + (srow + 64) * 32 + skc) = va1;
    *(bf16x8*)(Bl + srow * 32 + skc)        = vb;
    __syncthreads();
    if (kk + 1 < 8) {
      const int k0 = (kk + 1) * 32;
      va0 = *(const bf16x8*)(A + (size_t)ra0 * C1 + k0 + skc);
      va1 = *(const bf16x8*)(A + (size_t)ra1 * C1 + k0 + skc);
      vb  = *(const bf16x8*)(Bt + (size_t)srow * C1 + k0 + skc);
    }
    bf16x8 af[4], bfr[2];
#pragma unroll
    for (int mi = 0; mi < 4; mi++)
      af[mi] = *(const bf16x8*)(Al + (wr + mi * 16 + lm) * 32 + q * 8);
#pragma unroll
    for (int ni = 0; ni < 2; ni++)
      bfr[ni] = *(const bf16x8*)(Bl + (wc + ni * 16 + lm) * 32 + q * 8);
#pragma unroll
    for (int mi = 0; mi < 4; mi++)
#pragma unroll
      for (int ni = 0; ni < 2; ni++)
        acc[mi][ni] = __builtin_amdgcn_mfma_f32_16x16x32_bf16(af[mi], bfr[ni], acc[mi][ni], 0, 0, 0);
  }

  // store h2b + per-wave partial score dots
  float ws[2], wd[2];
#pragma unroll
  for (int ni = 0; ni < 2; ni++) {
    ws[ni] = asw[wc + ni * 16 + lm];
    wd[ni] = adw[wc + ni * 16 + lm];
  }
#pragma unroll
  for (int mi = 0; mi < 4; mi++) {
#pragma unroll
    for (int ni = 0; ni < 2; ni++) {
      const int col = wc + ni * 16 + lm;
#pragma unroll
      for (int r = 0; r < 4; r++) {
        const int row = bm + wr + mi * 16 + q * 4 + r;
        if (row < M) C[(size_t)row * CLS + col] = (__bf16)acc[mi][ni][r];
      }
    }
#pragma unroll
    for (int r = 0; r < 4; r++) {
      float ps = acc[mi][0][r] * ws[0] + acc[mi][1][r] * ws[1];
      float pd = acc[mi][0][r] * wd[0] + acc[mi][1][r] * wd[1];
#pragma unroll
      for (int o = 1; o <= 8; o <<= 1) { ps += __shfl_xor(ps, o); pd += __shfl_xor(pd, o); }
      if (lm == 0) {
        const int rl = wr + mi * 16 + q * 4 + r;
        sred[rl][wave & 1][0] = ps;
        sred[rl][wave & 1][1] = pd;
      }
    }
  }
  __syncthreads();
  if (tid < 128) {
    const int row = bm + tid;
    if (row < M) {
      a_src[row] = sred[tid][0][0] + sred[tid][1][0];
      a_dst[row] = sred[tid][0][1] + sred[tid][1][1];
    }
  }
}

// ---------------- layer-1 gather (proven: ~75µs) ----------------
__global__ __launch_bounds__(256) void gather1(const int* __restrict__ rowstart,
    const int* __restrict__ csr_src, const __bf16* __restrict__ h1,
    const float* __restrict__ as1, const float* __restrict__ ad1,
    const float* __restrict__ b1, __bf16* __restrict__ o1, int N) {
  const int t = threadIdx.x;
  const int d = blockIdx.x * 4 + (t >> 6);
  if (d >= N) return;
  const int lane = t & 63;
  const int e8 = lane >> 3, hh = lane & 7;
  const int r0 = rowstart[d];
  const int deg = rowstart[d + 1] - r0;

  const float addh = ad1[(size_t)d * 8 + hh];
  const float self_sc = leaky(as1[(size_t)d * 8 + hh] + addh);

  int   se[8];
  float sc[8];
#pragma unroll
  for (int ch = 0; ch < 8; ch++) {
    const int j = ch * 8 + e8;
    se[ch] = 0; sc[ch] = -3.4e38f;
    if (j < deg) {
      int s = csr_src[r0 + j];
      se[ch] = s;
      sc[ch] = leaky(as1[(size_t)s * 8 + hh] + addh);
    }
  }
  float mx = -3.4e38f;
#pragma unroll
  for (int ch = 0; ch < 8; ch++) mx = fmaxf(mx, sc[ch]);
  for (int j0 = 64; j0 < deg; j0 += 8) {
    int j = j0 + e8;
    if (j < deg) {
      int s = csr_src[r0 + j];
      mx = fmaxf(mx, leaky(as1[(size_t)s * 8 + hh] + addh));
    }
  }
  mx = fmaxf(mx, __shfl_xor(mx, 8));
  mx = fmaxf(mx, __shfl_xor(mx, 16));
  mx = fmaxf(mx, __shfl_xor(mx, 32));
  mx = fmaxf(mx, self_sc);

  float sum = 0.f;
#pragma unroll
  for (int ch = 0; ch < 8; ch++)
    if (ch * 8 + e8 < deg) sum += __expf(sc[ch] - mx);
  for (int j0 = 64; j0 < deg; j0 += 8) {
    int j = j0 + e8;
    if (j < deg) {
      int s = csr_src[r0 + j];
      sum += __expf(leaky(as1[(size_t)s * 8 + hh] + addh) - mx);
    }
  }
  sum += __shfl_xor(sum, 8);
  sum += __shfl_xor(sum, 16);
  sum += __shfl_xor(sum, 32);
  sum += __expf(self_sc - mx);
  const float inv = 1.f / (sum + EPS);

  float al[8];
#pragma unroll
  for (int ch = 0; ch < 8; ch++) al[ch] = __expf(sc[ch] - mx) * inv;
  const float al_self_byhh = __expf(self_sc - mx) * inv;

  const int p = lane >> 5, g = lane & 31, hg = g >> 2;
  float acc[8];
#pragma unroll
  for (int i = 0; i < 8; i++) acc[i] = 0.f;

#pragma unroll
  for (int it = 0; it < 32; it++) {
    if (it * 2 < deg) {
      const int   j   = it * 2 + p;
      const int   s_j = __shfl(se[it >> 2], (j & 7) * 8);
      const float a_j = __shfl(al[it >> 2], (j & 7) * 8 + hg);
      bf16x8 x = *(const bf16x8*)(h1 + (size_t)s_j * C1 + g * 8);
#pragma unroll
      for (int i = 0; i < 8; i++) acc[i] += a_j * (float)x[i];
    }
  }
  for (int j0 = 64; j0 < deg; j0 += 8) {
    int j = j0 + e8;
    int se2 = 0; float al2 = 0.f;
    if (j < deg) { se2 = csr_src[r0 + j]; al2 = __expf(leaky(as1[(size_t)se2 * 8 + hh] + addh) - mx) * inv; }
#pragma unroll
    for (int it = 0; it < 4; it++) {
      if (j0 + it * 2 < deg) {
        const int   jj  = it * 2 + p;
        const int   s_j = __shfl(se2, jj * 8);
        const float a_j = __shfl(al2, jj * 8 + hg);
        bf16x8 x = *(const bf16x8*)(h1 + (size_t)s_j * C1 + g * 8);
#pragma unroll
        for (int i = 0; i < 8; i++) acc[i] += a_j * (float)x[i];
      }
    }
  }
#pragma unroll
  for (int i = 0; i < 8; i++) acc[i] += __shfl_xor(acc[i], 32);

  const float a_selfh = __shfl(al_self_byhh, hg);
  if (lane < 32) {
    bf16x8 xs = *(const bf16x8*)(h1 + (size_t)d * C1 + g * 8);
    const float4 b4a = *(const float4*)(b1 + g * 8);
    const float4 b4b = *(const float4*)(b1 + g * 8 + 4);
    bf16x8 o;
    o[0] = (__bf16)fmaxf(acc[0] + a_selfh * (float)xs[0] + b4a.x, 0.f);
    o[1] = (__bf16)fmaxf(acc[1] + a_selfh * (float)xs[1] + b4a.y, 0.f);
    o[2] = (__bf16)fmaxf(acc[2] + a_selfh * (float)xs[2] + b4a.z, 0.f);
    o[3] = (__bf16)fmaxf(acc[3] + a_selfh * (float)xs[3] + b4a.w, 0.f);
    o[4] = (__bf16)fmaxf(acc[4] + a_selfh * (float)xs[4] + b4b.x, 0.f);
    o[5] = (__bf16)fmaxf(acc[5] + a_selfh * (float)xs[5] + b4b.y, 0.f);
    o[6] = (__bf16)fmaxf(acc[6] + a_selfh * (float)xs[6] + b4b.z, 0.f);
    o[7] = (__bf16)fmaxf(acc[7] + a_selfh * (float)xs[7] + b4b.w, 0.f);
    *(bf16x8*)(o1 + (size_t)d * C1 + g * 8) = o;
  }
}

// ---------------- layer-2 gather + fused bias + log_softmax ----------------
__global__ __launch_bounds__(256) void gather2(const int* __restrict__ rowstart,
    const int* __restrict__ csr_src, const __bf16* __restrict__ h2b,
    const float* __restrict__ as2, const float* __restrict__ ad2,
    const float* __restrict__ b2, float* __restrict__ out, int N) {
  const int t = threadIdx.x, lane = t & 63;
  const int d = blockIdx.x * 4 + (t >> 6);
  if (d >= N) return;
  const int r0 = rowstart[d], deg = rowstart[d + 1] - r0;
  const float addd = ad2[d];
  const float self_sc = leaky(as2[d] + addd);

  int se = 0; float sc = -3.4e38f;
  if (lane < deg) { se = csr_src[r0 + lane]; sc = leaky(as2[se] + addd); }
  float mx = sc;
  for (int j0 = 64; j0 < deg; j0 += 64) {
    int j = j0 + lane;
    if (j < deg) mx = fmaxf(mx, leaky(as2[csr_src[r0 + j]] + addd));
  }
#pragma unroll
  for (int o = 1; o < 64; o <<= 1) mx = fmaxf(mx, __shfl_xor(mx, o));
  mx = fmaxf(mx, self_sc);

  float ex = (lane < deg) ? __expf(sc - mx) : 0.f;
  float sum = ex;
  for (int j0 = 64; j0 < deg; j0 += 64) {
    int j = j0 + lane;
    if (j < deg) sum += __expf(leaky(as2[csr_src[r0 + j]] + addd) - mx);
  }
#pragma unroll
  for (int o = 1; o < 64; o <<= 1) sum += __shfl_xor(sum, o);
  const float e_self = __expf(self_sc - mx);
  sum += e_self;
  const float inv = 1.f / (sum + EPS);
  const float alpha = ex * inv;
  const float al_self = e_self * inv;

  const int e8 = lane >> 3, c8 = lane & 7;
  float acc[8];
#pragma unroll
  for (int i = 0; i < 8; i++) acc[i] = 0.f;

#pragma unroll
  for (int it = 0; it < 8; it++) {
    if (it * 8 < deg) {
      const int   j   = it * 8 + e8;
      const int   s_j = __shfl(se, j);
      const float a_j = __shfl(alpha, j);
      bf16x8 x = *(const bf16x8*)(h2b + (size_t)s_j * CLS + c8 * 8);
#pragma unroll
      for (int i = 0; i < 8; i++) acc[i] += a_j * (float)x[i];
    }
  }
  for (int j0 = 64; j0 < deg; j0 += 64) {
    int j = j0 + lane;
    int se2 = 0; float al2 = 0.f;
    if (j < deg) { se2 = csr_src[r0 + j]; al2 = __expf(leaky(as2[se2] + addd) - mx) * inv; }
#pragma unroll
    for (int it = 0; it < 8; it++) {
      if (j0 + it * 8 < deg) {
        const int   jj  = it * 8 + e8;
        const int   s_j = __shfl(se2, jj);
        const float a_j = __shfl(al2, jj);
        bf16x8 x = *(const bf16x8*)(h2b + (size_t)s_j * CLS + c8 * 8);
#pragma unroll
        for (int i = 0; i < 8; i++) acc[i] += a_j * (float)x[i];
      }
    }
  }
#pragma unroll
  for (int i = 0; i < 8; i++) {
    acc[i] += __shfl_xor(acc[i], 8);
    acc[i] += __shfl_xor(acc[i], 16);
    acc[i] += __shfl_xor(acc[i], 32);
  }

  bf16x8 xs = *(const bf16x8*)(h2b + (size_t)d * CLS + c8 * 8);
  const float4 bba = *(const float4*)(b2 + c8 * 8);
  const float4 bbb = *(const float4*)(b2 + c8 * 8 + 4);
  float v[8];
  v[0] = acc[0] + al_self * (float)xs[0] + bba.x;
  v[1] = acc[1] + al_self * (float)xs[1] + bba.y;
  v[2] = acc[2] + al_self * (float)xs[2] + bba.z;
  v[3] = acc[3] + al_self * (float)xs[3] + bba.w;
  v[4] = acc[4] + al_self * (float)xs[4] + bbb.x;
  v[5] = acc[5] + al_self * (float)xs[5] + bbb.y;
  v[6] = acc[6] + al_self * (float)xs[6] + bbb.z;
  v[7] = acc[7] + al_self * (float)xs[7] + bbb.w;
  float m2 = v[0];
#pragma unroll
  for (int i = 1; i < 8; i++) m2 = fmaxf(m2, v[i]);
  m2 = fmaxf(m2, __shfl_xor(m2, 1));
  m2 = fmaxf(m2, __shfl_xor(m2, 2));
  m2 = fmaxf(m2, __shfl_xor(m2, 4));
  float sm = 0.f;
#pragma unroll
  for (int i = 0; i < 8; i++) sm += __expf(v[i] - m2);
  sm += __shfl_xor(sm, 1);
  sm += __shfl_xor(sm, 2);
  sm += __shfl_xor(sm, 4);
  const float lg = m2 + __logf(sm);
  if (lane < 8) {
    float4 o0, o1v;
    o0.x  = v[0] - lg; o0.y  = v[1] - lg; o0.z  = v[2] - lg; o0.w  = v[3] - lg;
    o1v.x = v[4] - lg; o1v.y = v[5] - lg; o1v.z = v[6] - lg; o1v.w = v[7] - lg;
    *(float4*)(out + (size_t)d * CLS + c8 * 8)     = o0;
    *(float4*)(out + (size_t)d * CLS + c8 * 8 + 4) = o1v;
  }
}

extern "C" void kernel_launch(void* const* d_in, const int* in_sizes, int n_in,
                              void* d_out, int out_size, void* d_ws, size_t ws_size,
                              hipStream_t stream) {
  const float* x        = (const float*)d_in[0];
  const int*   ei       = (const int*)d_in[1];
  const float* W1       = (const float*)d_in[2];
  const float* att_src1 = (const float*)d_in[3];
  const float* att_dst1 = (const float*)d_in[4];
  const float* b1       = (const float*)d_in[5];
  const float* W2       = (const float*)d_in[6];
  const float* att_src2 = (const float*)d_in[7];
  const float* att_dst2 = (const float*)d_in[8];
  const float* b2       = (const float*)d_in[9];
  float* out = (float*)d_out;

  const int N  = in_sizes[0] / F_IN;   // 50000
  const int E  = in_sizes[1] / 2;      // 800000
  const int NB = (N + 255) / 256;

  char* ws = (char*)d_ws;
  size_t off = 0;
  auto alloc = [&](size_t bytes) -> void* {
    void* p = ws + off;
    off += (bytes + 255) & ~(size_t)255;
    return p;
  };
  __bf16* h1  = (__bf16*)alloc((size_t)N * C1 * 2);
  __bf16* o1  = (__bf16*)alloc((size_t)N * C1 * 2);
  float*  as1 = (float*)alloc((size_t)N * HEADS * 4);
  float*  ad1 = (float*)alloc((size_t)N * HEADS * 4);
  __bf16* h2b = (__bf16*)alloc((size_t)N * CLS * 2);
  float*  as2 = (float*)alloc((size_t)N * 4);
  float*  ad2 = (float*)alloc((size_t)N * 4);
  int* deg      = (int*)alloc((size_t)N * 4);
  int* rowstart = (int*)alloc((size_t)(N + 1) * 4);
  int* cur      = (int*)alloc((size_t)N * 4);
  int* csr_src  = (int*)alloc((size_t)E * 4);
  int* bsum     = (int*)alloc((size_t)NB * 4);
  __bf16* w1t = (__bf16*)alloc((size_t)C1 * F_IN * 2);
  __bf16* w2t = (__bf16*)alloc((size_t)CLS * C1 * 2);

  // ---- prep: weight casts + degree histogram ----
  hipMemsetAsync(deg, 0, (size_t)N * 4, stream);
  prep<<<72 + (E + 255) / 256, 256, 0, stream>>>(W1, W2, ei, w1t, w2t, deg, E);

  // ---- parallel scan -> rowstart, cur ----
  scan_k1<<<NB, 256, 0, stream>>>(deg, bsum, N);
  scan_k2<<<1, 256, 0, stream>>>(bsum, NB);
  scan_k3<<<NB, 256, 0, stream>>>(deg, bsum, rowstart, cur, N);
  scatter_csr<<<(E + 255) / 256, 256, 0, stream>>>(ei, cur, csr_src, E);

  // ---- layer 1: GEMM + scores fused ----
  gemm1_fused<<<(N + 127) / 128, 256, 0, stream>>>(x, w1t, h1, att_src1, att_dst1, as1, ad1, N);
  gather1<<<(N + 3) / 4, 256, 0, stream>>>(rowstart, csr_src, h1, as1, ad1, b1, o1, N);

  // ---- layer 2: GEMM + scores fused ----
  gemm2_fused<<<(N + 127) / 128, 256, 0, stream>>>(o1, w2t, h2b, att_src2, att_dst2, as2, ad2, N);
  gather2<<<(N + 3) / 4, 256, 0, stream>>>(rowstart, csr_src, h2b, as2, ad2, b2, out, N);
}

// Round 10
// 411.414 us; speedup vs baseline: 1.5513x; 1.0038x over previous
//
#include <hip/hip_runtime.h>
#include <hip/hip_bf16.h>
#include <stdint.h>

#define F_IN 512
#define HID 32
#define HEADS 8
#define C1 (HEADS*HID)   // 256
#define CLS 64
#define NEG 0.2f
#define EPS 1e-16f

typedef __bf16 bf16x8 __attribute__((ext_vector_type(8)));
typedef __bf16 bf16x4 __attribute__((ext_vector_type(4)));
typedef float  f32x4  __attribute__((ext_vector_type(4)));

__device__ __forceinline__ float leaky(float v) { return v > 0.f ? v : NEG * v; }

__device__ __forceinline__ bf16x8 cvt8(float4 a, float4 b) {
  bf16x8 o;
  o[0] = (__bf16)a.x; o[1] = (__bf16)a.y; o[2] = (__bf16)a.z; o[3] = (__bf16)a.w;
  o[4] = (__bf16)b.x; o[5] = (__bf16)b.y; o[6] = (__bf16)b.z; o[7] = (__bf16)b.w;
  return o;
}

// ---------------- fused prep: cvt_w1t | cvt_w2t | count_deg ----------------
__global__ __launch_bounds__(256) void prep(const float* __restrict__ W1,
    const float* __restrict__ W2, const int* __restrict__ ei,
    __bf16* __restrict__ w1t, __bf16* __restrict__ w2t,
    int* __restrict__ deg, int E) {
  const int b = blockIdx.x, t = threadIdx.x;
  if (b < 64) {
    int i = b * 256 + t;
    int o0 = i * 8;
    int c = o0 >> 9, k0 = o0 & 511;
    bf16x8 o;
#pragma unroll
    for (int j = 0; j < 8; j++) o[j] = (__bf16)W1[(size_t)(k0 + j) * C1 + c];
    *(bf16x8*)(w1t + (size_t)o0) = o;
  } else if (b < 72) {
    int i = (b - 64) * 256 + t;
    int o0 = i * 8;
    int c = o0 >> 8, k0 = o0 & 255;
    bf16x8 o;
#pragma unroll
    for (int j = 0; j < 8; j++) o[j] = (__bf16)W2[(size_t)(k0 + j) * CLS + c];
    *(bf16x8*)(w2t + (size_t)o0) = o;
  } else {
    int e = (b - 72) * 256 + t;
    if (e < E) atomicAdd(&deg[ei[E + e]], 1);
  }
}

// ---------------- parallel exclusive scan ----------------
__global__ __launch_bounds__(256) void scan_k1(const int* __restrict__ deg,
    int* __restrict__ bsum, int N) {
  __shared__ int ws[4];
  const int t = threadIdx.x, lane = t & 63, wid = t >> 6;
  int i = blockIdx.x * 256 + t;
  int v = (i < N) ? deg[i] : 0;
#pragma unroll
  for (int o = 1; o < 64; o <<= 1) v += __shfl_xor(v, o);
  if (lane == 0) ws[wid] = v;
  __syncthreads();
  if (t == 0) bsum[blockIdx.x] = ws[0] + ws[1] + ws[2] + ws[3];
}

__global__ __launch_bounds__(256) void scan_k2(int* __restrict__ bsum, int nb) {
  __shared__ int wsum[4];
  __shared__ int carry_s;
  const int t = threadIdx.x, lane = t & 63, wid = t >> 6;
  if (t == 0) carry_s = 0;
  __syncthreads();
  for (int base = 0; base < nb; base += 256) {
    int i = base + t;
    int v = (i < nb) ? bsum[i] : 0;
    int inc = v;
#pragma unroll
    for (int o = 1; o < 64; o <<= 1) { int x = __shfl_up(inc, o); if (lane >= o) inc += x; }
    if (lane == 63) wsum[wid] = inc;
    __syncthreads();
    int woff = 0;
    for (int w = 0; w < wid; w++) woff += wsum[w];
    int excl = carry_s + woff + inc - v;
    if (i < nb) bsum[i] = excl;
    __syncthreads();
    if (t == 0) carry_s += wsum[0] + wsum[1] + wsum[2] + wsum[3];
    __syncthreads();
  }
}

__global__ __launch_bounds__(256) void scan_k3(const int* __restrict__ deg,
    const int* __restrict__ bsum, int* __restrict__ rowstart,
    int* __restrict__ cur, int N) {
  __shared__ int wsum[4];
  const int t = threadIdx.x, lane = t & 63, wid = t >> 6;
  int i = blockIdx.x * 256 + t;
  int v = (i < N) ? deg[i] : 0;
  int inc = v;
#pragma unroll
  for (int o = 1; o < 64; o <<= 1) { int x = __shfl_up(inc, o); if (lane >= o) inc += x; }
  if (lane == 63) wsum[wid] = inc;
  __syncthreads();
  int woff = 0;
  for (int w = 0; w < wid; w++) woff += wsum[w];
  int excl = bsum[blockIdx.x] + woff + inc - v;
  if (i < N) { rowstart[i] = excl; cur[i] = excl; }
  if (i == N - 1) rowstart[N] = excl + v;
}

__global__ __launch_bounds__(256) void scatter_csr(const int* __restrict__ ei,
    int* __restrict__ cur, int* __restrict__ csr_src, int E) {
  int e = blockIdx.x * 256 + threadIdx.x;
  if (e >= E) return;
  int s = ei[e], d = ei[E + e];
  int pos = atomicAdd(&cur[d], 1);
  csr_src[pos] = s;
}

// ---------------- GEMM1 fused: h1 = x @ w1t^T (BN=128, proven tile) + scores for 4 heads ----------------
// grid (2, ceil(M/128)); block bn covers cols bn*128..+127 = heads bn*4..bn*4+3 (disjoint -> no atomics)
__global__ __launch_bounds__(256) void gemm1_fused(const float* __restrict__ A,
    const __bf16* __restrict__ Bt, __bf16* __restrict__ C,
    const float* __restrict__ asw, const float* __restrict__ adw,
    float* __restrict__ a_src, float* __restrict__ a_dst, int M) {
  __shared__ __bf16 Al[128 * 32];
  __shared__ __bf16 Bl[128 * 32];
  const int tid = threadIdx.x, lane = tid & 63, wave = tid >> 6;
  const int lm = lane & 15, q = lane >> 4;
  const int wr = (wave >> 1) * 64, wc = (wave & 1) * 64;
  const int bm = blockIdx.y * 128, bn = blockIdx.x * 128;
  const int srow = tid >> 2, skc = (tid & 3) * 8;

  f32x4 acc[4][4];
#pragma unroll
  for (int i = 0; i < 4; i++)
#pragma unroll
    for (int j = 0; j < 4; j++) acc[i][j] = (f32x4){0.f, 0.f, 0.f, 0.f};

  const int ra0 = min(bm + srow, M - 1);
  const int ra1 = min(bm + srow + 64, M - 1);
  const int rb0 = bn + srow, rb1 = bn + srow + 64;

  float4 a00, a01, a10, a11;
  bf16x8 vb0, vb1;
  a00 = *(const float4*)(A + (size_t)ra0 * 512 + skc);
  a01 = *(const float4*)(A + (size_t)ra0 * 512 + skc + 4);
  a10 = *(const float4*)(A + (size_t)ra1 * 512 + skc);
  a11 = *(const float4*)(A + (size_t)ra1 * 512 + skc + 4);
  vb0 = *(const bf16x8*)(Bt + (size_t)rb0 * 512 + skc);
  vb1 = *(const bf16x8*)(Bt + (size_t)rb1 * 512 + skc);

  for (int kk = 0; kk < 16; kk++) {
    __syncthreads();
    *(bf16x8*)(Al + srow * 32 + skc)        = cvt8(a00, a01);
    *(bf16x8*)(Al + (srow + 64) * 32 + skc) = cvt8(a10, a11);
    *(bf16x8*)(Bl + srow * 32 + skc)        = vb0;
    *(bf16x8*)(Bl + (srow + 64) * 32 + skc) = vb1;
    __syncthreads();
    if (kk + 1 < 16) {
      const int k0 = (kk + 1) * 32;
      a00 = *(const float4*)(A + (size_t)ra0 * 512 + k0 + skc);
      a01 = *(const float4*)(A + (size_t)ra0 * 512 + k0 + skc + 4);
      a10 = *(const float4*)(A + (size_t)ra1 * 512 + k0 + skc);
      a11 = *(const float4*)(A + (size_t)ra1 * 512 + k0 + skc + 4);
      vb0 = *(const bf16x8*)(Bt + (size_t)rb0 * 512 + k0 + skc);
      vb1 = *(const bf16x8*)(Bt + (size_t)rb1 * 512 + k0 + skc);
    }
    bf16x8 af[4], bfr[4];
#pragma unroll
    for (int mi = 0; mi < 4; mi++)
      af[mi] = *(const bf16x8*)(Al + (wr + mi * 16 + lm) * 32 + q * 8);
#pragma unroll
    for (int ni = 0; ni < 4; ni++)
      bfr[ni] = *(const bf16x8*)(Bl + (wc + ni * 16 + lm) * 32 + q * 8);
#pragma unroll
    for (int mi = 0; mi < 4; mi++)
#pragma unroll
      for (int ni = 0; ni < 4; ni++)
        acc[mi][ni] = __builtin_amdgcn_mfma_f32_16x16x32_bf16(af[mi], bfr[ni], acc[mi][ni], 0, 0, 0);
  }

  // store h1 (bf16)
#pragma unroll
  for (int mi = 0; mi < 4; mi++) {
#pragma unroll
    for (int ni = 0; ni < 4; ni++) {
      const int col = bn + wc + ni * 16 + lm;
#pragma unroll
      for (int r = 0; r < 4; r++) {
        const int row = bm + wr + mi * 16 + q * 4 + r;
        if (row < M) C[(size_t)row * C1 + col] = (__bf16)acc[mi][ni][r];
      }
    }
  }

  // fused scores from fp32 acc: this wave covers heads h0, h0+1 (cols bn+wc .. +63)
  {
    const int cb = bn + wc;
    const int h0 = cb >> 5;
    float ws[4], wd[4];
#pragma unroll
    for (int ni = 0; ni < 4; ni++) {
      ws[ni] = asw[cb + ni * 16 + lm];
      wd[ni] = adw[cb + ni * 16 + lm];
    }
#pragma unroll
    for (int mi = 0; mi < 4; mi++) {
#pragma unroll
      for (int r = 0; r < 4; r++) {
        float ps0 = acc[mi][0][r] * ws[0] + acc[mi][1][r] * ws[1];
        float ps1 = acc[mi][2][r] * ws[2] + acc[mi][3][r] * ws[3];
        float pd0 = acc[mi][0][r] * wd[0] + acc[mi][1][r] * wd[1];
        float pd1 = acc[mi][2][r] * wd[2] + acc[mi][3][r] * wd[3];
#pragma unroll
        for (int o = 1; o <= 8; o <<= 1) {
          ps0 += __shfl_xor(ps0, o); ps1 += __shfl_xor(ps1, o);
          pd0 += __shfl_xor(pd0, o); pd1 += __shfl_xor(pd1, o);
        }
        if (lm == 0) {
          const int row = bm + wr + mi * 16 + q * 4 + r;
          if (row < M) {
            a_src[(size_t)row * 8 + h0]     = ps0;
            a_src[(size_t)row * 8 + h0 + 1] = ps1;
            a_dst[(size_t)row * 8 + h0]     = pd0;
            a_dst[(size_t)row * 8 + h0 + 1] = pd1;
          }
        }
      }
    }
  }
}

// ---------------- GEMM2 fused: h2b = o1 @ w2t^T (bf16 out) + att scores 2 ----------------
__global__ __launch_bounds__(256) void gemm2_fused(const __bf16* __restrict__ A,
    const __bf16* __restrict__ Bt, __bf16* __restrict__ C,
    const float* __restrict__ asw, const float* __restrict__ adw,
    float* __restrict__ a_src, float* __restrict__ a_dst, int M) {
  __shared__ __bf16 Al[128 * 32];
  __shared__ __bf16 Bl[64 * 32];
  __shared__ float sred[128][2][2];
  const int tid = threadIdx.x, lane = tid & 63, wave = tid >> 6;
  const int lm = lane & 15, q = lane >> 4;
  const int wr = (wave >> 1) * 64, wc = (wave & 1) * 32;
  const int bm = blockIdx.x * 128;
  const int srow = tid >> 2, skc = (tid & 3) * 8;

  f32x4 acc[4][2];
#pragma unroll
  for (int i = 0; i < 4; i++)
#pragma unroll
    for (int j = 0; j < 2; j++) acc[i][j] = (f32x4){0.f, 0.f, 0.f, 0.f};

  const int ra0 = min(bm + srow, M - 1);
  const int ra1 = min(bm + srow + 64, M - 1);

  bf16x8 va0, va1, vb;
  va0 = *(const bf16x8*)(A + (size_t)ra0 * C1 + skc);
  va1 = *(const bf16x8*)(A + (size_t)ra1 * C1 + skc);
  vb  = *(const bf16x8*)(Bt + (size_t)srow * C1 + skc);

  for (int kk = 0; kk < 8; kk++) {
    __syncthreads();
    *(bf16x8*)(Al + srow * 32 + skc)        = va0;
    *(bf16x8*)(Al + (srow + 64) * 32 + skc) = va1;
    *(bf16x8*)(Bl + srow * 32 + skc)        = vb;
    __syncthreads();
    if (kk + 1 < 8) {
      const int k0 = (kk + 1) * 32;
      va0 = *(const bf16x8*)(A + (size_t)ra0 * C1 + k0 + skc);
      va1 = *(const bf16x8*)(A + (size_t)ra1 * C1 + k0 + skc);
      vb  = *(const bf16x8*)(Bt + (size_t)srow * C1 + k0 + skc);
    }
    bf16x8 af[4], bfr[2];
#pragma unroll
    for (int mi = 0; mi < 4; mi++)
      af[mi] = *(const bf16x8*)(Al + (wr + mi * 16 + lm) * 32 + q * 8);
#pragma unroll
    for (int ni = 0; ni < 2; ni++)
      bfr[ni] = *(const bf16x8*)(Bl + (wc + ni * 16 + lm) * 32 + q * 8);
#pragma unroll
    for (int mi = 0; mi < 4; mi++)
#pragma unroll
      for (int ni = 0; ni < 2; ni++)
        acc[mi][ni] = __builtin_amdgcn_mfma_f32_16x16x32_bf16(af[mi], bfr[ni], acc[mi][ni], 0, 0, 0);
  }

  float ws[2], wd[2];
#pragma unroll
  for (int ni = 0; ni < 2; ni++) {
    ws[ni] = asw[wc + ni * 16 + lm];
    wd[ni] = adw[wc + ni * 16 + lm];
  }
#pragma unroll
  for (int mi = 0; mi < 4; mi++) {
#pragma unroll
    for (int ni = 0; ni < 2; ni++) {
      const int col = wc + ni * 16 + lm;
#pragma unroll
      for (int r = 0; r < 4; r++) {
        const int row = bm + wr + mi * 16 + q * 4 + r;
        if (row < M) C[(size_t)row * CLS + col] = (__bf16)acc[mi][ni][r];
      }
    }
#pragma unroll
    for (int r = 0; r < 4; r++) {
      float ps = acc[mi][0][r] * ws[0] + acc[mi][1][r] * ws[1];
      float pd = acc[mi][0][r] * wd[0] + acc[mi][1][r] * wd[1];
#pragma unroll
      for (int o = 1; o <= 8; o <<= 1) { ps += __shfl_xor(ps, o); pd += __shfl_xor(pd, o); }
      if (lm == 0) {
        const int rl = wr + mi * 16 + q * 4 + r;
        sred[rl][wave & 1][0] = ps;
        sred[rl][wave & 1][1] = pd;
      }
    }
  }
  __syncthreads();
  if (tid < 128) {
    const int row = bm + tid;
    if (row < M) {
      a_src[row] = sred[tid][0][0] + sred[tid][1][0];
      a_dst[row] = sred[tid][0][1] + sred[tid][1][1];
    }
  }
}

// ---------------- layer-1 gather (proven: ~75µs) ----------------
__global__ __launch_bounds__(256) void gather1(const int* __restrict__ rowstart,
    const int* __restrict__ csr_src, const __bf16* __restrict__ h1,
    const float* __restrict__ as1, const float* __restrict__ ad1,
    const float* __restrict__ b1, __bf16* __restrict__ o1, int N) {
  const int t = threadIdx.x;
  const int d = blockIdx.x * 4 + (t >> 6);
  if (d >= N) return;
  const int lane = t & 63;
  const int e8 = lane >> 3, hh = lane & 7;
  const int r0 = rowstart[d];
  const int deg = rowstart[d + 1] - r0;

  const float addh = ad1[(size_t)d * 8 + hh];
  const float self_sc = leaky(as1[(size_t)d * 8 + hh] + addh);

  int   se[8];
  float sc[8];
#pragma unroll
  for (int ch = 0; ch < 8; ch++) {
    const int j = ch * 8 + e8;
    se[ch] = 0; sc[ch] = -3.4e38f;
    if (j < deg) {
      int s = csr_src[r0 + j];
      se[ch] = s;
      sc[ch] = leaky(as1[(size_t)s * 8 + hh] + addh);
    }
  }
  float mx = -3.4e38f;
#pragma unroll
  for (int ch = 0; ch < 8; ch++) mx = fmaxf(mx, sc[ch]);
  for (int j0 = 64; j0 < deg; j0 += 8) {
    int j = j0 + e8;
    if (j < deg) {
      int s = csr_src[r0 + j];
      mx = fmaxf(mx, leaky(as1[(size_t)s * 8 + hh] + addh));
    }
  }
  mx = fmaxf(mx, __shfl_xor(mx, 8));
  mx = fmaxf(mx, __shfl_xor(mx, 16));
  mx = fmaxf(mx, __shfl_xor(mx, 32));
  mx = fmaxf(mx, self_sc);

  float sum = 0.f;
#pragma unroll
  for (int ch = 0; ch < 8; ch++)
    if (ch * 8 + e8 < deg) sum += __expf(sc[ch] - mx);
  for (int j0 = 64; j0 < deg; j0 += 8) {
    int j = j0 + e8;
    if (j < deg) {
      int s = csr_src[r0 + j];
      sum += __expf(leaky(as1[(size_t)s * 8 + hh] + addh) - mx);
    }
  }
  sum += __shfl_xor(sum, 8);
  sum += __shfl_xor(sum, 16);
  sum += __shfl_xor(sum, 32);
  sum += __expf(self_sc - mx);
  const float inv = 1.f / (sum + EPS);

  float al[8];
#pragma unroll
  for (int ch = 0; ch < 8; ch++) al[ch] = __expf(sc[ch] - mx) * inv;
  const float al_self_byhh = __expf(self_sc - mx) * inv;

  const int p = lane >> 5, g = lane & 31, hg = g >> 2;
  float acc[8];
#pragma unroll
  for (int i = 0; i < 8; i++) acc[i] = 0.f;

#pragma unroll
  for (int it = 0; it < 32; it++) {
    if (it * 2 < deg) {
      const int   j   = it * 2 + p;
      const int   s_j = __shfl(se[it >> 2], (j & 7) * 8);
      const float a_j = __shfl(al[it >> 2], (j & 7) * 8 + hg);
      bf16x8 x = *(const bf16x8*)(h1 + (size_t)s_j * C1 + g * 8);
#pragma unroll
      for (int i = 0; i < 8; i++) acc[i] += a_j * (float)x[i];
    }
  }
  for (int j0 = 64; j0 < deg; j0 += 8) {
    int j = j0 + e8;
    int se2 = 0; float al2 = 0.f;
    if (j < deg) { se2 = csr_src[r0 + j]; al2 = __expf(leaky(as1[(size_t)se2 * 8 + hh] + addh) - mx) * inv; }
#pragma unroll
    for (int it = 0; it < 4; it++) {
      if (j0 + it * 2 < deg) {
        const int   jj  = it * 2 + p;
        const int   s_j = __shfl(se2, jj * 8);
        const float a_j = __shfl(al2, jj * 8 + hg);
        bf16x8 x = *(const bf16x8*)(h1 + (size_t)s_j * C1 + g * 8);
#pragma unroll
        for (int i = 0; i < 8; i++) acc[i] += a_j * (float)x[i];
      }
    }
  }
#pragma unroll
  for (int i = 0; i < 8; i++) acc[i] += __shfl_xor(acc[i], 32);

  const float a_selfh = __shfl(al_self_byhh, hg);
  if (lane < 32) {
    bf16x8 xs = *(const bf16x8*)(h1 + (size_t)d * C1 + g * 8);
    const float4 b4a = *(const float4*)(b1 + g * 8);
    const float4 b4b = *(const float4*)(b1 + g * 8 + 4);
    bf16x8 o;
    o[0] = (__bf16)fmaxf(acc[0] + a_selfh * (float)xs[0] + b4a.x, 0.f);
    o[1] = (__bf16)fmaxf(acc[1] + a_selfh * (float)xs[1] + b4a.y, 0.f);
    o[2] = (__bf16)fmaxf(acc[2] + a_selfh * (float)xs[2] + b4a.z, 0.f);
    o[3] = (__bf16)fmaxf(acc[3] + a_selfh * (float)xs[3] + b4a.w, 0.f);
    o[4] = (__bf16)fmaxf(acc[4] + a_selfh * (float)xs[4] + b4b.x, 0.f);
    o[5] = (__bf16)fmaxf(acc[5] + a_selfh * (float)xs[5] + b4b.y, 0.f);
    o[6] = (__bf16)fmaxf(acc[6] + a_selfh * (float)xs[6] + b4b.z, 0.f);
    o[7] = (__bf16)fmaxf(acc[7] + a_selfh * (float)xs[7] + b4b.w, 0.f);
    *(bf16x8*)(o1 + (size_t)d * C1 + g * 8) = o;
  }
}

// ---------------- layer-2 gather + fused bias + log_softmax ----------------
__global__ __launch_bounds__(256) void gather2(const int* __restrict__ rowstart,
    const int* __restrict__ csr_src, const __bf16* __restrict__ h2b,
    const float* __restrict__ as2, const float* __restrict__ ad2,
    const float* __restrict__ b2, float* __restrict__ out, int N) {
  const int t = threadIdx.x, lane = t & 63;
  const int d = blockIdx.x * 4 + (t >> 6);
  if (d >= N) return;
  const int r0 = rowstart[d], deg = rowstart[d + 1] - r0;
  const float addd = ad2[d];
  const float self_sc = leaky(as2[d] + addd);

  int se = 0; float sc = -3.4e38f;
  if (lane < deg) { se = csr_src[r0 + lane]; sc = leaky(as2[se] + addd); }
  float mx = sc;
  for (int j0 = 64; j0 < deg; j0 += 64) {
    int j = j0 + lane;
    if (j < deg) mx = fmaxf(mx, leaky(as2[csr_src[r0 + j]] + addd));
  }
#pragma unroll
  for (int o = 1; o < 64; o <<= 1) mx = fmaxf(mx, __shfl_xor(mx, o));
  mx = fmaxf(mx, self_sc);

  float ex = (lane < deg) ? __expf(sc - mx) : 0.f;
  float sum = ex;
  for (int j0 = 64; j0 < deg; j0 += 64) {
    int j = j0 + lane;
    if (j < deg) sum += __expf(leaky(as2[csr_src[r0 + j]] + addd) - mx);
  }
#pragma unroll
  for (int o = 1; o < 64; o <<= 1) sum += __shfl_xor(sum, o);
  const float e_self = __expf(self_sc - mx);
  sum += e_self;
  const float inv = 1.f / (sum + EPS);
  const float alpha = ex * inv;
  const float al_self = e_self * inv;

  const int e8 = lane >> 3, c8 = lane & 7;
  float acc[8];
#pragma unroll
  for (int i = 0; i < 8; i++) acc[i] = 0.f;

#pragma unroll
  for (int it = 0; it < 8; it++) {
    if (it * 8 < deg) {
      const int   j   = it * 8 + e8;
      const int   s_j = __shfl(se, j);
      const float a_j = __shfl(alpha, j);
      bf16x8 x = *(const bf16x8*)(h2b + (size_t)s_j * CLS + c8 * 8);
#pragma unroll
      for (int i = 0; i < 8; i++) acc[i] += a_j * (float)x[i];
    }
  }
  for (int j0 = 64; j0 < deg; j0 += 64) {
    int j = j0 + lane;
    int se2 = 0; float al2 = 0.f;
    if (j < deg) { se2 = csr_src[r0 + j]; al2 = __expf(leaky(as2[se2] + addd) - mx) * inv; }
#pragma unroll
    for (int it = 0; it < 8; it++) {
      if (j0 + it * 8 < deg) {
        const int   jj  = it * 8 + e8;
        const int   s_j = __shfl(se2, jj);
        const float a_j = __shfl(al2, jj);
        bf16x8 x = *(const bf16x8*)(h2b + (size_t)s_j * CLS + c8 * 8);
#pragma unroll
        for (int i = 0; i < 8; i++) acc[i] += a_j * (float)x[i];
      }
    }
  }
#pragma unroll
  for (int i = 0; i < 8; i++) {
    acc[i] += __shfl_xor(acc[i], 8);
    acc[i] += __shfl_xor(acc[i], 16);
    acc[i] += __shfl_xor(acc[i], 32);
  }

  bf16x8 xs = *(const bf16x8*)(h2b + (size_t)d * CLS + c8 * 8);
  const float4 bba = *(const float4*)(b2 + c8 * 8);
  const float4 bbb = *(const float4*)(b2 + c8 * 8 + 4);
  float v[8];
  v[0] = acc[0] + al_self * (float)xs[0] + bba.x;
  v[1] = acc[1] + al_self * (float)xs[1] + bba.y;
  v[2] = acc[2] + al_self * (float)xs[2] + bba.z;
  v[3] = acc[3] + al_self * (float)xs[3] + bba.w;
  v[4] = acc[4] + al_self * (float)xs[4] + bbb.x;
  v[5] = acc[5] + al_self * (float)xs[5] + bbb.y;
  v[6] = acc[6] + al_self * (float)xs[6] + bbb.z;
  v[7] = acc[7] + al_self * (float)xs[7] + bbb.w;
  float m2 = v[0];
#pragma unroll
  for (int i = 1; i < 8; i++) m2 = fmaxf(m2, v[i]);
  m2 = fmaxf(m2, __shfl_xor(m2, 1));
  m2 = fmaxf(m2, __shfl_xor(m2, 2));
  m2 = fmaxf(m2, __shfl_xor(m2, 4));
  float sm = 0.f;
#pragma unroll
  for (int i = 0; i < 8; i++) sm += __expf(v[i] - m2);
  sm += __shfl_xor(sm, 1);
  sm += __shfl_xor(sm, 2);
  sm += __shfl_xor(sm, 4);
  const float lg = m2 + __logf(sm);
  if (lane < 8) {
    float4 o0, o1v;
    o0.x  = v[0] - lg; o0.y  = v[1] - lg; o0.z  = v[2] - lg; o0.w  = v[3] - lg;
    o1v.x = v[4] - lg; o1v.y = v[5] - lg; o1v.z = v[6] - lg; o1v.w = v[7] - lg;
    *(float4*)(out + (size_t)d * CLS + c8 * 8)     = o0;
    *(float4*)(out + (size_t)d * CLS + c8 * 8 + 4) = o1v;
  }
}

extern "C" void kernel_launch(void* const* d_in, const int* in_sizes, int n_in,
                              void* d_out, int out_size, void* d_ws, size_t ws_size,
                              hipStream_t stream) {
  const float* x        = (const float*)d_in[0];
  const int*   ei       = (const int*)d_in[1];
  const float* W1       = (const float*)d_in[2];
  const float* att_src1 = (const float*)d_in[3];
  const float* att_dst1 = (const float*)d_in[4];
  const float* b1       = (const float*)d_in[5];
  const float* W2       = (const float*)d_in[6];
  const float* att_src2 = (const float*)d_in[7];
  const float* att_dst2 = (const float*)d_in[8];
  const float* b2       = (const float*)d_in[9];
  float* out = (float*)d_out;

  const int N  = in_sizes[0] / F_IN;   // 50000
  const int E  = in_sizes[1] / 2;      // 800000
  const int NB = (N + 255) / 256;

  char* ws = (char*)d_ws;
  size_t off = 0;
  auto alloc = [&](size_t bytes) -> void* {
    void* p = ws + off;
    off += (bytes + 255) & ~(size_t)255;
    return p;
  };
  __bf16* h1  = (__bf16*)alloc((size_t)N * C1 * 2);
  __bf16* o1  = (__bf16*)alloc((size_t)N * C1 * 2);
  float*  as1 = (float*)alloc((size_t)N * HEADS * 4);
  float*  ad1 = (float*)alloc((size_t)N * HEADS * 4);
  __bf16* h2b = (__bf16*)alloc((size_t)N * CLS * 2);
  float*  as2 = (float*)alloc((size_t)N * 4);
  float*  ad2 = (float*)alloc((size_t)N * 4);
  int* deg      = (int*)alloc((size_t)N * 4);
  int* rowstart = (int*)alloc((size_t)(N + 1) * 4);
  int* cur      = (int*)alloc((size_t)N * 4);
  int* csr_src  = (int*)alloc((size_t)E * 4);
  int* bsum     = (int*)alloc((size_t)NB * 4);
  __bf16* w1t = (__bf16*)alloc((size_t)C1 * F_IN * 2);
  __bf16* w2t = (__bf16*)alloc((size_t)CLS * C1 * 2);

  // ---- prep: weight casts + degree histogram ----
  hipMemsetAsync(deg, 0, (size_t)N * 4, stream);
  prep<<<72 + (E + 255) / 256, 256, 0, stream>>>(W1, W2, ei, w1t, w2t, deg, E);

  // ---- parallel scan -> rowstart, cur ----
  scan_k1<<<NB, 256, 0, stream>>>(deg, bsum, N);
  scan_k2<<<1, 256, 0, stream>>>(bsum, NB);
  scan_k3<<<NB, 256, 0, stream>>>(deg, bsum, rowstart, cur, N);
  scatter_csr<<<(E + 255) / 256, 256, 0, stream>>>(ei, cur, csr_src, E);

  // ---- layer 1: GEMM + scores fused (BN=128 tile) ----
  {
    dim3 g(C1 / 128, (N + 127) / 128);
    gemm1_fused<<<g, 256, 0, stream>>>(x, w1t, h1, att_src1, att_dst1, as1, ad1, N);
  }
  gather1<<<(N + 3) / 4, 256, 0, stream>>>(rowstart, csr_src, h1, as1, ad1, b1, o1, N);

  // ---- layer 2: GEMM + scores fused ----
  gemm2_fused<<<(N + 127) / 128, 256, 0, stream>>>(o1, w2t, h2b, att_src2, att_dst2, as2, ad2, N);
  gather2<<<(N + 3) / 4, 256, 0, stream>>>(rowstart, csr_src, h2b, as2, ad2, b2, out, N);
}